// Round 6
// baseline (857.558 us; speedup 1.0000x reference)
//
#include <hip/hip_runtime.h>
#include <hip/hip_fp16.h>
#include <math.h>

#define DIM 128
#define GR 64          // rows per GEMM block
#define ALD 132        // A-tile LDS row stride (floats): %4==0 for b128, %32==4 -> conflict-free
#define POOL_SPLIT 32  // partial-sum blocks per graph
// CSR build: 256-node buckets x 8 pseudo-XCD (blockIdx%8) sub-streams.
// Writer locality is the whole point: per-XCD L2s are not coherent, so a
// cache line only merges its 8 records if all writers sit on one XCD.

// ---------------------------------------------------------------------------
// Graph build kernels
// ---------------------------------------------------------------------------

// counts[d]++ (per-node, for rowptr/deg) and cnt8[bucket*8+pseudoXCD]++
__global__ void count_k(const int* __restrict__ dst, int* __restrict__ counts,
                        int* __restrict__ cnt8, int E) {
    int e = blockIdx.x * 256 + threadIdx.x;
    if (e < E) {
        int d = dst[e];
        atomicAdd(&counts[d], 1);
        atomicAdd(&cnt8[((d >> 8) << 3) + (blockIdx.x & 7)], 1);
    }
}

// per-block inclusive scan of counts -> incl, block sums -> bsum
__global__ void scan1_k(const int* __restrict__ counts, int* __restrict__ incl,
                        int* __restrict__ bsum, int n) {
    __shared__ int s[256];
    int i = blockIdx.x * 256 + threadIdx.x;
    int v = (i < n) ? counts[i] : 0;
    s[threadIdx.x] = v;
    __syncthreads();
    for (int off = 1; off < 256; off <<= 1) {
        int t = (threadIdx.x >= (unsigned)off) ? s[threadIdx.x - off] : 0;
        __syncthreads();
        s[threadIdx.x] += t;
        __syncthreads();
    }
    if (i < n) incl[i] = s[threadIdx.x];
    if (threadIdx.x == 255) bsum[blockIdx.x] = s[255];
}

// single-block scan of block sums (nb <= 512), in-place -> exclusive
__global__ void scan2_k(int* __restrict__ bsum, int nb) {
    __shared__ int s[512];
    int v = (threadIdx.x < (unsigned)nb) ? bsum[threadIdx.x] : 0;
    s[threadIdx.x] = v;
    __syncthreads();
    for (int off = 1; off < 512; off <<= 1) {
        int t = (threadIdx.x >= (unsigned)off) ? s[threadIdx.x - off] : 0;
        __syncthreads();
        s[threadIdx.x] += t;
        __syncthreads();
    }
    bsum[threadIdx.x] = s[threadIdx.x] - v;  // exclusive
}

// finalize: rowptr (exclusive), dis = rsqrt(deg) with deg = counts+1 (self loop)
__global__ void scan3_k(const int* __restrict__ counts, const int* __restrict__ incl,
                        const int* __restrict__ bsum, int* __restrict__ rowptr,
                        float* __restrict__ dis, int n, int E) {
    int i = blockIdx.x * 256 + threadIdx.x;
    if (i < n) {
        int excl = incl[i] - counts[i] + bsum[blockIdx.x];
        rowptr[i] = excl;
        dis[i]    = rsqrtf((float)(counts[i] + 1));
    }
    if (i == 0) rowptr[n] = E;
}

// per-bucket serial scan of its 8 sub-stream counts -> append cursors
__global__ void bscan_k(const int* __restrict__ rowptr, const int* __restrict__ cnt8,
                        int* __restrict__ cursor8, int NB) {
    int b = blockIdx.x * 256 + threadIdx.x;
    if (b < NB) {
        int base = rowptr[b << 8];   // b*256 < n for all b < NB
        for (int p = 0; p < 8; ++p) {
            cursor8[b * 8 + p] = base;
            base += cnt8[b * 8 + p];
        }
    }
}

// append {src,dst} to the (bucket, blockIdx%8) sub-stream
__global__ void bucket_k(const int* __restrict__ src, const int* __restrict__ dst,
                         int* __restrict__ cursor8, int2* __restrict__ tmp, int E) {
    int e = blockIdx.x * 256 + threadIdx.x;
    if (e < E) {
        int s = src[e], d = dst[e];
        int pos = atomicAdd(&cursor8[((d >> 8) << 3) + (blockIdx.x & 7)], 1);
        tmp[pos] = make_int2(s, d);
    }
}

// one block per 256-node bucket: place records into final CSR slots via LDS
// cursors; all writes land in this block's ~35KB ew region -> full line merge.
__global__ __launch_bounds__(256) void fill2_k(const int2* __restrict__ tmp,
                                               const int* __restrict__ rowptr,
                                               const float* __restrict__ dis,
                                               int2* __restrict__ ew, int n) {
    __shared__ int lcur[256];
    const int base_node = blockIdx.x << 8;
    const int i = threadIdx.x;
    if (base_node + i < n) lcur[i] = rowptr[base_node + i];
    const int e_begin = rowptr[base_node];
    const int e_end   = rowptr[min(base_node + 256, n)];
    __syncthreads();
    for (int e = e_begin + i; e < e_end; e += 256) {
        int2 r = tmp[e];
        float w = dis[r.x] * dis[r.y];
        int q = atomicAdd(&lcur[r.y & 255], 1);
        ew[q] = make_int2(r.x, __float_as_int(w));
    }
}

// ---------------------------------------------------------------------------
// GEMM: T[n,128](fp16) = A[n,128] @ W[128,128]; A is fp32 (layer 0) or fp16.
// fp32 accumulate; A tile staged (and widened) into LDS, W from L1/L2.
// ---------------------------------------------------------------------------
template <bool FP16IN>
__global__ __launch_bounds__(256) void gemm_k(const void* __restrict__ Ain,
                                              const float* __restrict__ W,
                                              __half* __restrict__ T, int n) {
    __shared__ float Al[GR * ALD];
    const int r0 = blockIdx.x * GR;
    const int t  = threadIdx.x;
    const int tx = t & 31;
    const int ty = t >> 5;

    const int nrows = min(GR, n - r0);
    if (FP16IN) {
        const __half* A = (const __half*)Ain;
        for (int idx = t; idx < GR * 16; idx += 256) {       // 16B = 8 halves
            int row = idx >> 4, c8 = idx & 15;
            float4 lo = make_float4(0.f, 0.f, 0.f, 0.f);
            float4 hi = make_float4(0.f, 0.f, 0.f, 0.f);
            if (row < nrows) {
                int4 raw = ((const int4*)(A + (size_t)(r0 + row) * DIM))[c8];
                const __half2* h = (const __half2*)&raw;
                float2 f0 = __half22float2(h[0]);
                float2 f1 = __half22float2(h[1]);
                float2 f2 = __half22float2(h[2]);
                float2 f3 = __half22float2(h[3]);
                lo = make_float4(f0.x, f0.y, f1.x, f1.y);
                hi = make_float4(f2.x, f2.y, f3.x, f3.y);
            }
            *(float4*)&Al[row * ALD + c8 * 8 + 0] = lo;
            *(float4*)&Al[row * ALD + c8 * 8 + 4] = hi;
        }
    } else {
        const float* A = (const float*)Ain;
        for (int idx = t; idx < GR * 32; idx += 256) {
            int row = idx >> 5, c4 = idx & 31;
            float4 v = make_float4(0.f, 0.f, 0.f, 0.f);
            if (row < nrows) v = ((const float4*)(A + (size_t)(r0 + row) * DIM))[c4];
            *(float4*)&Al[row * ALD + c4 * 4] = v;
        }
    }
    __syncthreads();

    float acc[8][4];
#pragma unroll
    for (int i = 0; i < 8; ++i)
#pragma unroll
        for (int j = 0; j < 4; ++j) acc[i][j] = 0.f;

    const float4* Wg = (const float4*)W;
    for (int k = 0; k < DIM; k += 4) {
        float4 w0 = Wg[(k + 0) * 32 + tx];
        float4 w1 = Wg[(k + 1) * 32 + tx];
        float4 w2 = Wg[(k + 2) * 32 + tx];
        float4 w3 = Wg[(k + 3) * 32 + tx];
#pragma unroll
        for (int i = 0; i < 8; ++i) {
            const float4 a4 = *(const float4*)&Al[(ty + 8 * i) * ALD + k];
            acc[i][0] += a4.x * w0.x; acc[i][1] += a4.x * w0.y;
            acc[i][2] += a4.x * w0.z; acc[i][3] += a4.x * w0.w;
            acc[i][0] += a4.y * w1.x; acc[i][1] += a4.y * w1.y;
            acc[i][2] += a4.y * w1.z; acc[i][3] += a4.y * w1.w;
            acc[i][0] += a4.z * w2.x; acc[i][1] += a4.z * w2.y;
            acc[i][2] += a4.z * w2.z; acc[i][3] += a4.z * w2.w;
            acc[i][0] += a4.w * w3.x; acc[i][1] += a4.w * w3.y;
            acc[i][2] += a4.w * w3.z; acc[i][3] += a4.w * w3.w;
        }
    }

#pragma unroll
    for (int i = 0; i < 8; ++i) {
        int row = ty + 8 * i;
        if (row < nrows) {
            __half2 lo = __floats2half2_rn(acc[i][0], acc[i][1]);
            __half2 hi = __floats2half2_rn(acc[i][2], acc[i][3]);
            int2 pk = make_int2(*(int*)&lo, *(int*)&hi);
            ((int2*)(T + (size_t)(r0 + row) * DIM))[tx] = pk;  // 8B = 4 halves
        }
    }
}

// ---------------------------------------------------------------------------
// Aggregation: O[v] = relu( dis[v]^2 * T[v] + sum_e wgt[e]*T[col[e]] + b )
// one wave per node; fp16 in, fp32 accumulate, fp16 out. Unrolled 8/4 for MLP.
// ---------------------------------------------------------------------------
__global__ __launch_bounds__(256) void agg_k(const __half* __restrict__ T,
                                             const int* __restrict__ rowptr,
                                             const int2* __restrict__ ew,
                                             const float* __restrict__ dis,
                                             const float* __restrict__ bias,
                                             __half* __restrict__ O, int n) {
    int lane = threadIdx.x & 63;
    int v = blockIdx.x * 4 + (threadIdx.x >> 6);
    if (v >= n) return;

    const __half2* T2 = (const __half2*)T;  // 64 half2 per row
    float dv = dis[v];
    int e0 = rowptr[v], e1 = rowptr[v + 1];

    float2 t = __half22float2(T2[(size_t)v * 64 + lane]);
    float2 acc;
    acc.x = t.x * dv * dv;
    acc.y = t.y * dv * dv;

    int e = e0;
    for (; e + 8 <= e1; e += 8) {
        int2 p0 = ew[e + 0], p1 = ew[e + 1], p2 = ew[e + 2], p3 = ew[e + 3];
        int2 p4 = ew[e + 4], p5 = ew[e + 5], p6 = ew[e + 6], p7 = ew[e + 7];
        float2 u0 = __half22float2(T2[(size_t)p0.x * 64 + lane]);
        float2 u1 = __half22float2(T2[(size_t)p1.x * 64 + lane]);
        float2 u2 = __half22float2(T2[(size_t)p2.x * 64 + lane]);
        float2 u3 = __half22float2(T2[(size_t)p3.x * 64 + lane]);
        float2 u4 = __half22float2(T2[(size_t)p4.x * 64 + lane]);
        float2 u5 = __half22float2(T2[(size_t)p5.x * 64 + lane]);
        float2 u6 = __half22float2(T2[(size_t)p6.x * 64 + lane]);
        float2 u7 = __half22float2(T2[(size_t)p7.x * 64 + lane]);
        float w0 = __int_as_float(p0.y), w1 = __int_as_float(p1.y);
        float w2 = __int_as_float(p2.y), w3 = __int_as_float(p3.y);
        float w4 = __int_as_float(p4.y), w5 = __int_as_float(p5.y);
        float w6 = __int_as_float(p6.y), w7 = __int_as_float(p7.y);
        acc.x += w0 * u0.x; acc.y += w0 * u0.y;
        acc.x += w1 * u1.x; acc.y += w1 * u1.y;
        acc.x += w2 * u2.x; acc.y += w2 * u2.y;
        acc.x += w3 * u3.x; acc.y += w3 * u3.y;
        acc.x += w4 * u4.x; acc.y += w4 * u4.y;
        acc.x += w5 * u5.x; acc.y += w5 * u5.y;
        acc.x += w6 * u6.x; acc.y += w6 * u6.y;
        acc.x += w7 * u7.x; acc.y += w7 * u7.y;
    }
    for (; e + 4 <= e1; e += 4) {
        int2 p0 = ew[e + 0], p1 = ew[e + 1], p2 = ew[e + 2], p3 = ew[e + 3];
        float2 u0 = __half22float2(T2[(size_t)p0.x * 64 + lane]);
        float2 u1 = __half22float2(T2[(size_t)p1.x * 64 + lane]);
        float2 u2 = __half22float2(T2[(size_t)p2.x * 64 + lane]);
        float2 u3 = __half22float2(T2[(size_t)p3.x * 64 + lane]);
        float w0 = __int_as_float(p0.y), w1 = __int_as_float(p1.y);
        float w2 = __int_as_float(p2.y), w3 = __int_as_float(p3.y);
        acc.x += w0 * u0.x; acc.y += w0 * u0.y;
        acc.x += w1 * u1.x; acc.y += w1 * u1.y;
        acc.x += w2 * u2.x; acc.y += w2 * u2.y;
        acc.x += w3 * u3.x; acc.y += w3 * u3.y;
    }
    for (; e < e1; ++e) {
        int2 p = ew[e];
        float w = __int_as_float(p.y);
        float2 u = __half22float2(T2[(size_t)p.x * 64 + lane]);
        acc.x += w * u.x;
        acc.y += w * u.y;
    }

    float2 b = ((const float2*)bias)[lane];
    __half2 o = __floats2half2_rn(fmaxf(acc.x + b.x, 0.f), fmaxf(acc.y + b.y, 0.f));
    ((__half2*)O)[(size_t)v * 64 + lane] = o;
}

// ---------------------------------------------------------------------------
// Global mean pool (fp16 in, fp32 out), split-parallel: grid (n_graphs, POOL_SPLIT)
// ---------------------------------------------------------------------------
__global__ __launch_bounds__(64) void pool_k(const __half* __restrict__ H,
                                             const int* __restrict__ batch,
                                             float* __restrict__ G, int n) {
    int g = blockIdx.x;
    int part = blockIdx.y;

    int lo = 0, hi = n;
    while (lo < hi) { int m = (lo + hi) >> 1; if (batch[m] < g) lo = m + 1; else hi = m; }
    int start = lo;
    lo = start; hi = n;
    while (lo < hi) { int m = (lo + hi) >> 1; if (batch[m] < g + 1) lo = m + 1; else hi = m; }
    int end = lo;
    int cnt = end - start;
    if (cnt <= 0) return;
    float inv = 1.0f / (float)cnt;

    int lane = threadIdx.x;
    const __half2* H2 = (const __half2*)H;
    float2 s = make_float2(0.f, 0.f);
    for (int v = start + part; v < end; v += POOL_SPLIT) {
        float2 h = __half22float2(H2[(size_t)v * 64 + lane]);
        s.x += h.x; s.y += h.y;
    }
    atomicAdd(&G[g * DIM + 2 * lane + 0], s.x * inv);
    atomicAdd(&G[g * DIM + 2 * lane + 1], s.y * inv);
}

// ---------------------------------------------------------------------------
// Head: y = relu(g@lin1+b1); logits = y@lin2+b2; out = log_softmax(logits)
// ---------------------------------------------------------------------------
__global__ __launch_bounds__(128) void head_k(const float* __restrict__ G,
                                              const float* __restrict__ l1w,
                                              const float* __restrict__ l1b,
                                              const float* __restrict__ l2w,
                                              const float* __restrict__ l2b,
                                              float* __restrict__ out) {
    int g = blockIdx.x;
    int j = threadIdx.x;
    __shared__ float gs[128];
    __shared__ float2 red[128];

    gs[j] = G[g * 128 + j];
    __syncthreads();

    float acc = l1b[j];
    for (int k = 0; k < 128; ++k) acc += gs[k] * l1w[k * 128 + j];
    float y = fmaxf(acc, 0.f);

    red[j] = make_float2(y * l2w[j * 2 + 0], y * l2w[j * 2 + 1]);
    __syncthreads();
    for (int s = 64; s > 0; s >>= 1) {
        if (j < s) {
            red[j].x += red[j + s].x;
            red[j].y += red[j + s].y;
        }
        __syncthreads();
    }
    if (j == 0) {
        float l0 = red[0].x + l2b[0];
        float l1 = red[0].y + l2b[1];
        float m = fmaxf(l0, l1);
        float lse = m + logf(expf(l0 - m) + expf(l1 - m));
        out[g * 2 + 0] = l0 - lse;
        out[g * 2 + 1] = l1 - lse;
    }
}

// ---------------------------------------------------------------------------
// Launch
// ---------------------------------------------------------------------------
extern "C" void kernel_launch(void* const* d_in, const int* in_sizes, int n_in,
                              void* d_out, int out_size, void* d_ws, size_t ws_size,
                              hipStream_t stream) {
    const float* x       = (const float*)d_in[0];
    const int*   ei      = (const int*)d_in[1];
    const int*   batch   = (const int*)d_in[2];
    const float* conv_w  = (const float*)d_in[3];
    const float* conv_b  = (const float*)d_in[4];
    const float* lin1_w  = (const float*)d_in[5];
    const float* lin1_b  = (const float*)d_in[6];
    const float* lin2_w  = (const float*)d_in[7];
    const float* lin2_b  = (const float*)d_in[8];
    float* out = (float*)d_out;

    const int n = in_sizes[0] / DIM;      // 100000
    const int E = in_sizes[1] / 2;        // 1600000
    const int n_graphs = 128;
    const int NB = (n + 255) >> 8;        // 256-node buckets (391)

    const int* src = ei;
    const int* dst = ei + E;

    // workspace layout (all 256B aligned)
    char* p = (char*)d_ws;
    auto alloc = [&](size_t bytes) {
        char* r = p;
        p += (bytes + 255) & ~(size_t)255;
        return r;
    };
    __half* bufH   = (__half*)alloc((size_t)n * DIM * 2);  // agg output (fp16)
    __half* bufT   = (__half*)alloc((size_t)n * DIM * 2);  // gemm output (fp16)
    float*  dis    = (float*)alloc((size_t)n * 4);
    int*    counts = (int*)alloc((size_t)n * 4);
    int*    incl   = (int*)alloc((size_t)n * 4);
    int*    rowptr = (int*)alloc((size_t)(n + 1) * 4);
    int*    bsum   = (int*)alloc(512 * 4);
    int*    cnt8   = (int*)alloc((size_t)NB * 8 * 4);
    int*    cursor8= (int*)alloc((size_t)NB * 8 * 4);
    int2*   tmp    = (int2*)alloc((size_t)E * 8);          // bucketed {src,dst}
    int2*   ew     = (int2*)alloc((size_t)E * 8);          // CSR {col, wgt}
    float*  gbuf   = (float*)alloc((size_t)n_graphs * DIM * 4);
    (void)ws_size;

    const int nScanBlocks = (n + 255) / 256;        // 391 (<=512)
    const int eBlocks = (E + 255) / 256;

    hipMemsetAsync(counts, 0, (size_t)n * 4, stream);
    hipMemsetAsync(cnt8, 0, (size_t)NB * 8 * 4, stream);
    hipMemsetAsync(gbuf, 0, (size_t)n_graphs * DIM * 4, stream);
    count_k<<<eBlocks, 256, 0, stream>>>(dst, counts, cnt8, E);
    scan1_k<<<nScanBlocks, 256, 0, stream>>>(counts, incl, bsum, n);
    scan2_k<<<1, 512, 0, stream>>>(bsum, nScanBlocks);
    scan3_k<<<nScanBlocks, 256, 0, stream>>>(counts, incl, bsum, rowptr, dis, n, E);
    bscan_k<<<(NB + 255) / 256, 256, 0, stream>>>(rowptr, cnt8, cursor8, NB);
    bucket_k<<<eBlocks, 256, 0, stream>>>(src, dst, cursor8, tmp, E);
    fill2_k<<<NB, 256, 0, stream>>>(tmp, rowptr, dis, ew, n);

    const int gemmBlocks = (n + GR - 1) / GR;
    const int aggBlocks = (n + 3) / 4;

    // layer 0: x (fp32) -> bufT -> bufH
    gemm_k<false><<<gemmBlocks, 256, 0, stream>>>((const void*)x, conv_w + 0 * DIM * DIM, bufT, n);
    agg_k<<<aggBlocks, 256, 0, stream>>>(bufT, rowptr, ew, dis, conv_b + 0 * DIM, bufH, n);
    // layer 1
    gemm_k<true><<<gemmBlocks, 256, 0, stream>>>((const void*)bufH, conv_w + 1 * DIM * DIM, bufT, n);
    agg_k<<<aggBlocks, 256, 0, stream>>>(bufT, rowptr, ew, dis, conv_b + 1 * DIM, bufH, n);
    // layer 2
    gemm_k<true><<<gemmBlocks, 256, 0, stream>>>((const void*)bufH, conv_w + 2 * DIM * DIM, bufT, n);
    agg_k<<<aggBlocks, 256, 0, stream>>>(bufT, rowptr, ew, dis, conv_b + 2 * DIM, bufH, n);

    dim3 pgrid(n_graphs, POOL_SPLIT);
    pool_k<<<pgrid, 64, 0, stream>>>(bufH, batch, gbuf, n);
    head_k<<<n_graphs, 128, 0, stream>>>(gbuf, lin1_w, lin1_b, lin2_w, lin2_b, out);
}

// Round 7
// 613.372 us; speedup vs baseline: 1.3981x; 1.3981x over previous
//
#include <hip/hip_runtime.h>
#include <hip/hip_fp16.h>
#include <math.h>

#define DIM 128
#define GR 64          // rows per GEMM block
#define ALD 132        // A-tile LDS row stride (floats): %4==0 for b128, %32==4 -> conflict-free
#define POOL_SPLIT 32  // partial-sum blocks per graph
#define BINSH 10       // 1024 nodes per dst-bin
#define EPB 16384      // edges per bin_k block
// Build discipline learned R6: per-edge global atomics onto few cache lines
// ping-pong across the 8 non-coherent XCD L2s (~50ns/bounce) — catastrophic.
// All per-edge counting happens in LDS; global atomics only per (block,bin).

// ---------------------------------------------------------------------------
// Graph build kernels
// ---------------------------------------------------------------------------

__global__ void count_k(const int* __restrict__ dst, int* __restrict__ counts, int E) {
    int e = blockIdx.x * 256 + threadIdx.x;
    if (e < E) atomicAdd(&counts[dst[e]], 1);
}

// per-block inclusive scan of counts -> incl, block sums -> bsum
__global__ void scan1_k(const int* __restrict__ counts, int* __restrict__ incl,
                        int* __restrict__ bsum, int n) {
    __shared__ int s[256];
    int i = blockIdx.x * 256 + threadIdx.x;
    int v = (i < n) ? counts[i] : 0;
    s[threadIdx.x] = v;
    __syncthreads();
    for (int off = 1; off < 256; off <<= 1) {
        int t = (threadIdx.x >= (unsigned)off) ? s[threadIdx.x - off] : 0;
        __syncthreads();
        s[threadIdx.x] += t;
        __syncthreads();
    }
    if (i < n) incl[i] = s[threadIdx.x];
    if (threadIdx.x == 255) bsum[blockIdx.x] = s[255];
}

// single-block scan of block sums (nb <= 512), in-place -> exclusive
__global__ void scan2_k(int* __restrict__ bsum, int nb) {
    __shared__ int s[512];
    int v = (threadIdx.x < (unsigned)nb) ? bsum[threadIdx.x] : 0;
    s[threadIdx.x] = v;
    __syncthreads();
    for (int off = 1; off < 512; off <<= 1) {
        int t = (threadIdx.x >= (unsigned)off) ? s[threadIdx.x - off] : 0;
        __syncthreads();
        s[threadIdx.x] += t;
        __syncthreads();
    }
    bsum[threadIdx.x] = s[threadIdx.x] - v;  // exclusive
}

// finalize: rowptr (exclusive), dis = rsqrt(deg) with deg = counts+1 (self loop)
__global__ void scan3_k(const int* __restrict__ counts, const int* __restrict__ incl,
                        const int* __restrict__ bsum, int* __restrict__ rowptr,
                        float* __restrict__ dis, int n, int E) {
    int i = blockIdx.x * 256 + threadIdx.x;
    if (i < n) {
        int excl = incl[i] - counts[i] + bsum[blockIdx.x];
        rowptr[i] = excl;
        dis[i]    = rsqrtf((float)(counts[i] + 1));
    }
    if (i == 0) rowptr[n] = E;
}

// init line-padded bin cursors: bincur[b*16] = rowptr[b<<BINSH]
__global__ void binscan_k(const int* __restrict__ rowptr, int* __restrict__ bincur, int NBIN) {
    int b = blockIdx.x * 256 + threadIdx.x;
    if (b < NBIN) bincur[b * 16] = rowptr[b << BINSH];
}

// pass 1: bin edges by dst>>BINSH. LDS histogram -> 1 reservation atomic per
// (block,bin) -> contiguous per-block runs => writes merge in this CU's L2.
__global__ __launch_bounds__(256) void bin_k(const int* __restrict__ src,
                                             const int* __restrict__ dst,
                                             int* __restrict__ bincur,
                                             int2* __restrict__ tmp, int E, int NBIN) {
    __shared__ int cur[128];
    const int t = threadIdx.x;
    if (t < 128) cur[t] = 0;
    __syncthreads();
    const int e0 = blockIdx.x * EPB;
    const int e1 = min(e0 + EPB, E);
    for (int e = e0 + t; e < e1; e += 256)
        atomicAdd(&cur[dst[e] >> BINSH], 1);
    __syncthreads();
    if (t < NBIN) {
        int h = cur[t];
        cur[t] = h ? atomicAdd(&bincur[t * 16], h) : 0;
    }
    __syncthreads();
    for (int e = e0 + t; e < e1; e += 256) {
        int d = dst[e], s = src[e];
        int pos = atomicAdd(&cur[d >> BINSH], 1);
        tmp[pos] = make_int2(s, d);
    }
}

// pass 2: one block per bin; LDS per-node cursors; place {src,wgt} into the
// bin's ~130KB CSR region (single-XCD writes -> full line merge).
__global__ __launch_bounds__(256) void fill2_k(const int2* __restrict__ tmp,
                                               const int* __restrict__ rowptr,
                                               const float* __restrict__ dis,
                                               int2* __restrict__ ew, int n) {
    __shared__ int lcur[1 << BINSH];
    const int base_node = blockIdx.x << BINSH;
    const int t = threadIdx.x;
    for (int i = t; i < (1 << BINSH); i += 256)
        if (base_node + i < n) lcur[i] = rowptr[base_node + i];
    const int e_begin = rowptr[base_node];
    const int e_end   = rowptr[min(base_node + (1 << BINSH), n)];
    __syncthreads();
    for (int e = e_begin + t; e < e_end; e += 256) {
        int2 r = tmp[e];
        float w = dis[r.x] * dis[r.y];
        int q = atomicAdd(&lcur[r.y & ((1 << BINSH) - 1)], 1);
        ew[q] = make_int2(r.x, __float_as_int(w));
    }
}

// ---------------------------------------------------------------------------
// GEMM: T[n,128](fp16) = A[n,128] @ W[128,128]; A is fp32 (layer 0) or fp16.
// fp32 accumulate; A tile staged (and widened) into LDS, W from L1/L2.
// ---------------------------------------------------------------------------
template <bool FP16IN>
__global__ __launch_bounds__(256) void gemm_k(const void* __restrict__ Ain,
                                              const float* __restrict__ W,
                                              __half* __restrict__ T, int n) {
    __shared__ float Al[GR * ALD];
    const int r0 = blockIdx.x * GR;
    const int t  = threadIdx.x;
    const int tx = t & 31;
    const int ty = t >> 5;

    const int nrows = min(GR, n - r0);
    if (FP16IN) {
        const __half* A = (const __half*)Ain;
        for (int idx = t; idx < GR * 16; idx += 256) {       // 16B = 8 halves
            int row = idx >> 4, c8 = idx & 15;
            float4 lo = make_float4(0.f, 0.f, 0.f, 0.f);
            float4 hi = make_float4(0.f, 0.f, 0.f, 0.f);
            if (row < nrows) {
                int4 raw = ((const int4*)(A + (size_t)(r0 + row) * DIM))[c8];
                const __half2* h = (const __half2*)&raw;
                float2 f0 = __half22float2(h[0]);
                float2 f1 = __half22float2(h[1]);
                float2 f2 = __half22float2(h[2]);
                float2 f3 = __half22float2(h[3]);
                lo = make_float4(f0.x, f0.y, f1.x, f1.y);
                hi = make_float4(f2.x, f2.y, f3.x, f3.y);
            }
            *(float4*)&Al[row * ALD + c8 * 8 + 0] = lo;
            *(float4*)&Al[row * ALD + c8 * 8 + 4] = hi;
        }
    } else {
        const float* A = (const float*)Ain;
        for (int idx = t; idx < GR * 32; idx += 256) {
            int row = idx >> 5, c4 = idx & 31;
            float4 v = make_float4(0.f, 0.f, 0.f, 0.f);
            if (row < nrows) v = ((const float4*)(A + (size_t)(r0 + row) * DIM))[c4];
            *(float4*)&Al[row * ALD + c4 * 4] = v;
        }
    }
    __syncthreads();

    float acc[8][4];
#pragma unroll
    for (int i = 0; i < 8; ++i)
#pragma unroll
        for (int j = 0; j < 4; ++j) acc[i][j] = 0.f;

    const float4* Wg = (const float4*)W;
    for (int k = 0; k < DIM; k += 4) {
        float4 w0 = Wg[(k + 0) * 32 + tx];
        float4 w1 = Wg[(k + 1) * 32 + tx];
        float4 w2 = Wg[(k + 2) * 32 + tx];
        float4 w3 = Wg[(k + 3) * 32 + tx];
#pragma unroll
        for (int i = 0; i < 8; ++i) {
            const float4 a4 = *(const float4*)&Al[(ty + 8 * i) * ALD + k];
            acc[i][0] += a4.x * w0.x; acc[i][1] += a4.x * w0.y;
            acc[i][2] += a4.x * w0.z; acc[i][3] += a4.x * w0.w;
            acc[i][0] += a4.y * w1.x; acc[i][1] += a4.y * w1.y;
            acc[i][2] += a4.y * w1.z; acc[i][3] += a4.y * w1.w;
            acc[i][0] += a4.z * w2.x; acc[i][1] += a4.z * w2.y;
            acc[i][2] += a4.z * w2.z; acc[i][3] += a4.z * w2.w;
            acc[i][0] += a4.w * w3.x; acc[i][1] += a4.w * w3.y;
            acc[i][2] += a4.w * w3.z; acc[i][3] += a4.w * w3.w;
        }
    }

#pragma unroll
    for (int i = 0; i < 8; ++i) {
        int row = ty + 8 * i;
        if (row < nrows) {
            __half2 lo = __floats2half2_rn(acc[i][0], acc[i][1]);
            __half2 hi = __floats2half2_rn(acc[i][2], acc[i][3]);
            int2 pk = make_int2(*(int*)&lo, *(int*)&hi);
            ((int2*)(T + (size_t)(r0 + row) * DIM))[tx] = pk;  // 8B = 4 halves
        }
    }
}

// ---------------------------------------------------------------------------
// Aggregation: O[v] = relu( dis[v]^2 * T[v] + sum_e wgt[e]*T[col[e]] + b )
// one wave per node; fp16 in, fp32 accumulate, fp16 out. Unrolled 8/4 for MLP.
// ---------------------------------------------------------------------------
__global__ __launch_bounds__(256) void agg_k(const __half* __restrict__ T,
                                             const int* __restrict__ rowptr,
                                             const int2* __restrict__ ew,
                                             const float* __restrict__ dis,
                                             const float* __restrict__ bias,
                                             __half* __restrict__ O, int n) {
    int lane = threadIdx.x & 63;
    int v = blockIdx.x * 4 + (threadIdx.x >> 6);
    if (v >= n) return;

    const __half2* T2 = (const __half2*)T;  // 64 half2 per row
    float dv = dis[v];
    int e0 = rowptr[v], e1 = rowptr[v + 1];

    float2 t = __half22float2(T2[(size_t)v * 64 + lane]);
    float2 acc;
    acc.x = t.x * dv * dv;
    acc.y = t.y * dv * dv;

    int e = e0;
    for (; e + 8 <= e1; e += 8) {
        int2 p0 = ew[e + 0], p1 = ew[e + 1], p2 = ew[e + 2], p3 = ew[e + 3];
        int2 p4 = ew[e + 4], p5 = ew[e + 5], p6 = ew[e + 6], p7 = ew[e + 7];
        float2 u0 = __half22float2(T2[(size_t)p0.x * 64 + lane]);
        float2 u1 = __half22float2(T2[(size_t)p1.x * 64 + lane]);
        float2 u2 = __half22float2(T2[(size_t)p2.x * 64 + lane]);
        float2 u3 = __half22float2(T2[(size_t)p3.x * 64 + lane]);
        float2 u4 = __half22float2(T2[(size_t)p4.x * 64 + lane]);
        float2 u5 = __half22float2(T2[(size_t)p5.x * 64 + lane]);
        float2 u6 = __half22float2(T2[(size_t)p6.x * 64 + lane]);
        float2 u7 = __half22float2(T2[(size_t)p7.x * 64 + lane]);
        float w0 = __int_as_float(p0.y), w1 = __int_as_float(p1.y);
        float w2 = __int_as_float(p2.y), w3 = __int_as_float(p3.y);
        float w4 = __int_as_float(p4.y), w5 = __int_as_float(p5.y);
        float w6 = __int_as_float(p6.y), w7 = __int_as_float(p7.y);
        acc.x += w0 * u0.x; acc.y += w0 * u0.y;
        acc.x += w1 * u1.x; acc.y += w1 * u1.y;
        acc.x += w2 * u2.x; acc.y += w2 * u2.y;
        acc.x += w3 * u3.x; acc.y += w3 * u3.y;
        acc.x += w4 * u4.x; acc.y += w4 * u4.y;
        acc.x += w5 * u5.x; acc.y += w5 * u5.y;
        acc.x += w6 * u6.x; acc.y += w6 * u6.y;
        acc.x += w7 * u7.x; acc.y += w7 * u7.y;
    }
    for (; e + 4 <= e1; e += 4) {
        int2 p0 = ew[e + 0], p1 = ew[e + 1], p2 = ew[e + 2], p3 = ew[e + 3];
        float2 u0 = __half22float2(T2[(size_t)p0.x * 64 + lane]);
        float2 u1 = __half22float2(T2[(size_t)p1.x * 64 + lane]);
        float2 u2 = __half22float2(T2[(size_t)p2.x * 64 + lane]);
        float2 u3 = __half22float2(T2[(size_t)p3.x * 64 + lane]);
        float w0 = __int_as_float(p0.y), w1 = __int_as_float(p1.y);
        float w2 = __int_as_float(p2.y), w3 = __int_as_float(p3.y);
        acc.x += w0 * u0.x; acc.y += w0 * u0.y;
        acc.x += w1 * u1.x; acc.y += w1 * u1.y;
        acc.x += w2 * u2.x; acc.y += w2 * u2.y;
        acc.x += w3 * u3.x; acc.y += w3 * u3.y;
    }
    for (; e < e1; ++e) {
        int2 p = ew[e];
        float w = __int_as_float(p.y);
        float2 u = __half22float2(T2[(size_t)p.x * 64 + lane]);
        acc.x += w * u.x;
        acc.y += w * u.y;
    }

    float2 b = ((const float2*)bias)[lane];
    __half2 o = __floats2half2_rn(fmaxf(acc.x + b.x, 0.f), fmaxf(acc.y + b.y, 0.f));
    ((__half2*)O)[(size_t)v * 64 + lane] = o;
}

// ---------------------------------------------------------------------------
// Global mean pool (fp16 in, fp32 out), split-parallel: grid (n_graphs, POOL_SPLIT)
// ---------------------------------------------------------------------------
__global__ __launch_bounds__(64) void pool_k(const __half* __restrict__ H,
                                             const int* __restrict__ batch,
                                             float* __restrict__ G, int n) {
    int g = blockIdx.x;
    int part = blockIdx.y;

    int lo = 0, hi = n;
    while (lo < hi) { int m = (lo + hi) >> 1; if (batch[m] < g) lo = m + 1; else hi = m; }
    int start = lo;
    lo = start; hi = n;
    while (lo < hi) { int m = (lo + hi) >> 1; if (batch[m] < g + 1) lo = m + 1; else hi = m; }
    int end = lo;
    int cnt = end - start;
    if (cnt <= 0) return;
    float inv = 1.0f / (float)cnt;

    int lane = threadIdx.x;
    const __half2* H2 = (const __half2*)H;
    float2 s = make_float2(0.f, 0.f);
    for (int v = start + part; v < end; v += POOL_SPLIT) {
        float2 h = __half22float2(H2[(size_t)v * 64 + lane]);
        s.x += h.x; s.y += h.y;
    }
    atomicAdd(&G[g * DIM + 2 * lane + 0], s.x * inv);
    atomicAdd(&G[g * DIM + 2 * lane + 1], s.y * inv);
}

// ---------------------------------------------------------------------------
// Head: y = relu(g@lin1+b1); logits = y@lin2+b2; out = log_softmax(logits)
// ---------------------------------------------------------------------------
__global__ __launch_bounds__(128) void head_k(const float* __restrict__ G,
                                              const float* __restrict__ l1w,
                                              const float* __restrict__ l1b,
                                              const float* __restrict__ l2w,
                                              const float* __restrict__ l2b,
                                              float* __restrict__ out) {
    int g = blockIdx.x;
    int j = threadIdx.x;
    __shared__ float gs[128];
    __shared__ float2 red[128];

    gs[j] = G[g * 128 + j];
    __syncthreads();

    float acc = l1b[j];
    for (int k = 0; k < 128; ++k) acc += gs[k] * l1w[k * 128 + j];
    float y = fmaxf(acc, 0.f);

    red[j] = make_float2(y * l2w[j * 2 + 0], y * l2w[j * 2 + 1]);
    __syncthreads();
    for (int s = 64; s > 0; s >>= 1) {
        if (j < s) {
            red[j].x += red[j + s].x;
            red[j].y += red[j + s].y;
        }
        __syncthreads();
    }
    if (j == 0) {
        float l0 = red[0].x + l2b[0];
        float l1 = red[0].y + l2b[1];
        float m = fmaxf(l0, l1);
        float lse = m + logf(expf(l0 - m) + expf(l1 - m));
        out[g * 2 + 0] = l0 - lse;
        out[g * 2 + 1] = l1 - lse;
    }
}

// ---------------------------------------------------------------------------
// Launch
// ---------------------------------------------------------------------------
extern "C" void kernel_launch(void* const* d_in, const int* in_sizes, int n_in,
                              void* d_out, int out_size, void* d_ws, size_t ws_size,
                              hipStream_t stream) {
    const float* x       = (const float*)d_in[0];
    const int*   ei      = (const int*)d_in[1];
    const int*   batch   = (const int*)d_in[2];
    const float* conv_w  = (const float*)d_in[3];
    const float* conv_b  = (const float*)d_in[4];
    const float* lin1_w  = (const float*)d_in[5];
    const float* lin1_b  = (const float*)d_in[6];
    const float* lin2_w  = (const float*)d_in[7];
    const float* lin2_b  = (const float*)d_in[8];
    float* out = (float*)d_out;

    const int n = in_sizes[0] / DIM;      // 100000
    const int E = in_sizes[1] / 2;        // 1600000
    const int n_graphs = 128;
    const int NBIN = (n + (1 << BINSH) - 1) >> BINSH;   // 98 dst-bins

    const int* src = ei;
    const int* dst = ei + E;

    // workspace layout (all 256B aligned)
    char* p = (char*)d_ws;
    auto alloc = [&](size_t bytes) {
        char* r = p;
        p += (bytes + 255) & ~(size_t)255;
        return r;
    };
    __half* bufH   = (__half*)alloc((size_t)n * DIM * 2);  // agg output (fp16)
    __half* bufT   = (__half*)alloc((size_t)n * DIM * 2);  // gemm output (fp16)
    float*  dis    = (float*)alloc((size_t)n * 4);
    int*    counts = (int*)alloc((size_t)n * 4);
    int*    incl   = (int*)alloc((size_t)n * 4);
    int*    rowptr = (int*)alloc((size_t)(n + 1) * 4);
    int*    bsum   = (int*)alloc(512 * 4);
    int*    bincur = (int*)alloc((size_t)NBIN * 16 * 4);   // line-padded cursors
    int2*   tmp    = (int2*)alloc((size_t)E * 8);          // binned {src,dst}
    int2*   ew     = (int2*)alloc((size_t)E * 8);          // CSR {col, wgt}
    float*  gbuf   = (float*)alloc((size_t)n_graphs * DIM * 4);
    (void)ws_size;

    const int nScanBlocks = (n + 255) / 256;        // 391 (<=512)
    const int eBlocks = (E + 255) / 256;
    const int binBlocks = (E + EPB - 1) / EPB;      // 98

    hipMemsetAsync(counts, 0, (size_t)n * 4, stream);
    hipMemsetAsync(gbuf, 0, (size_t)n_graphs * DIM * 4, stream);
    count_k<<<eBlocks, 256, 0, stream>>>(dst, counts, E);
    scan1_k<<<nScanBlocks, 256, 0, stream>>>(counts, incl, bsum, n);
    scan2_k<<<1, 512, 0, stream>>>(bsum, nScanBlocks);
    scan3_k<<<nScanBlocks, 256, 0, stream>>>(counts, incl, bsum, rowptr, dis, n, E);
    binscan_k<<<(NBIN + 255) / 256, 256, 0, stream>>>(rowptr, bincur, NBIN);
    bin_k<<<binBlocks, 256, 0, stream>>>(src, dst, bincur, tmp, E, NBIN);
    fill2_k<<<NBIN, 256, 0, stream>>>(tmp, rowptr, dis, ew, n);

    const int gemmBlocks = (n + GR - 1) / GR;
    const int aggBlocks = (n + 3) / 4;

    // layer 0: x (fp32) -> bufT -> bufH
    gemm_k<false><<<gemmBlocks, 256, 0, stream>>>((const void*)x, conv_w + 0 * DIM * DIM, bufT, n);
    agg_k<<<aggBlocks, 256, 0, stream>>>(bufT, rowptr, ew, dis, conv_b + 0 * DIM, bufH, n);
    // layer 1
    gemm_k<true><<<gemmBlocks, 256, 0, stream>>>((const void*)bufH, conv_w + 1 * DIM * DIM, bufT, n);
    agg_k<<<aggBlocks, 256, 0, stream>>>(bufT, rowptr, ew, dis, conv_b + 1 * DIM, bufH, n);
    // layer 2
    gemm_k<true><<<gemmBlocks, 256, 0, stream>>>((const void*)bufH, conv_w + 2 * DIM * DIM, bufT, n);
    agg_k<<<aggBlocks, 256, 0, stream>>>(bufT, rowptr, ew, dis, conv_b + 2 * DIM, bufH, n);

    dim3 pgrid(n_graphs, POOL_SPLIT);
    pool_k<<<pgrid, 64, 0, stream>>>(bufH, batch, gbuf, n);
    head_k<<<n_graphs, 128, 0, stream>>>(gbuf, lin1_w, lin1_b, lin2_w, lin2_b, out);
}

// Round 8
// 536.666 us; speedup vs baseline: 1.5979x; 1.1429x over previous
//
#include <hip/hip_runtime.h>
#include <hip/hip_fp16.h>
#include <math.h>

#define DIM 128
#define POOL_SPLIT 32  // partial-sum blocks per graph
#define BINSH 10       // 1024 nodes per dst-bin
#define EPB 16384      // edges per bin_k block
// Build discipline learned R6: per-edge global atomics onto few cache lines
// ping-pong across the 8 non-coherent XCD L2s (~50ns/bounce) — catastrophic.
// All per-edge counting happens in LDS; global atomics only per (block,bin).

typedef __attribute__((ext_vector_type(8))) _Float16 half8;
typedef __attribute__((ext_vector_type(4))) float f32x4;

// ---------------------------------------------------------------------------
// Graph build kernels
// ---------------------------------------------------------------------------

__global__ void count_k(const int* __restrict__ dst, int* __restrict__ counts, int E) {
    int e = blockIdx.x * 256 + threadIdx.x;
    if (e < E) atomicAdd(&counts[dst[e]], 1);
}

// per-block inclusive scan of counts -> incl, block sums -> bsum
__global__ void scan1_k(const int* __restrict__ counts, int* __restrict__ incl,
                        int* __restrict__ bsum, int n) {
    __shared__ int s[256];
    int i = blockIdx.x * 256 + threadIdx.x;
    int v = (i < n) ? counts[i] : 0;
    s[threadIdx.x] = v;
    __syncthreads();
    for (int off = 1; off < 256; off <<= 1) {
        int t = (threadIdx.x >= (unsigned)off) ? s[threadIdx.x - off] : 0;
        __syncthreads();
        s[threadIdx.x] += t;
        __syncthreads();
    }
    if (i < n) incl[i] = s[threadIdx.x];
    if (threadIdx.x == 255) bsum[blockIdx.x] = s[255];
}

// single-block scan of block sums (nb <= 512), in-place -> exclusive
__global__ void scan2_k(int* __restrict__ bsum, int nb) {
    __shared__ int s[512];
    int v = (threadIdx.x < (unsigned)nb) ? bsum[threadIdx.x] : 0;
    s[threadIdx.x] = v;
    __syncthreads();
    for (int off = 1; off < 512; off <<= 1) {
        int t = (threadIdx.x >= (unsigned)off) ? s[threadIdx.x - off] : 0;
        __syncthreads();
        s[threadIdx.x] += t;
        __syncthreads();
    }
    bsum[threadIdx.x] = s[threadIdx.x] - v;  // exclusive
}

// finalize: rowptr (exclusive), dis = rsqrt(deg) with deg = counts+1 (self loop)
__global__ void scan3_k(const int* __restrict__ counts, const int* __restrict__ incl,
                        const int* __restrict__ bsum, int* __restrict__ rowptr,
                        float* __restrict__ dis, int n, int E) {
    int i = blockIdx.x * 256 + threadIdx.x;
    if (i < n) {
        int excl = incl[i] - counts[i] + bsum[blockIdx.x];
        rowptr[i] = excl;
        dis[i]    = rsqrtf((float)(counts[i] + 1));
    }
    if (i == 0) rowptr[n] = E;
}

// init line-padded bin cursors: bincur[b*16] = rowptr[b<<BINSH]
__global__ void binscan_k(const int* __restrict__ rowptr, int* __restrict__ bincur, int NBIN) {
    int b = blockIdx.x * 256 + threadIdx.x;
    if (b < NBIN) bincur[b * 16] = rowptr[b << BINSH];
}

// pass 1: bin edges by dst>>BINSH. LDS histogram -> 1 reservation atomic per
// (block,bin) -> contiguous per-block runs => writes merge in this CU's L2.
__global__ __launch_bounds__(256) void bin_k(const int* __restrict__ src,
                                             const int* __restrict__ dst,
                                             int* __restrict__ bincur,
                                             int2* __restrict__ tmp, int E, int NBIN) {
    __shared__ int cur[128];
    const int t = threadIdx.x;
    if (t < 128) cur[t] = 0;
    __syncthreads();
    const int e0 = blockIdx.x * EPB;
    const int e1 = min(e0 + EPB, E);
    for (int e = e0 + t; e < e1; e += 256)
        atomicAdd(&cur[dst[e] >> BINSH], 1);
    __syncthreads();
    if (t < NBIN) {
        int h = cur[t];
        cur[t] = h ? atomicAdd(&bincur[t * 16], h) : 0;
    }
    __syncthreads();
    for (int e = e0 + t; e < e1; e += 256) {
        int d = dst[e], s = src[e];
        int pos = atomicAdd(&cur[d >> BINSH], 1);
        tmp[pos] = make_int2(s, d);
    }
}

// pass 2: one block per bin; LDS per-node cursors; place {src,wgt} into the
// bin's ~130KB CSR region (single-XCD writes -> full line merge).
__global__ __launch_bounds__(256) void fill2_k(const int2* __restrict__ tmp,
                                               const int* __restrict__ rowptr,
                                               const float* __restrict__ dis,
                                               int2* __restrict__ ew, int n) {
    __shared__ int lcur[1 << BINSH];
    const int base_node = blockIdx.x << BINSH;
    const int t = threadIdx.x;
    for (int i = t; i < (1 << BINSH); i += 256)
        if (base_node + i < n) lcur[i] = rowptr[base_node + i];
    const int e_begin = rowptr[base_node];
    const int e_end   = rowptr[min(base_node + (1 << BINSH), n)];
    __syncthreads();
    for (int e = e_begin + t; e < e_end; e += 256) {
        int2 r = tmp[e];
        float w = dis[r.x] * dis[r.y];
        int q = atomicAdd(&lcur[r.y & ((1 << BINSH) - 1)], 1);
        ew[q] = make_int2(r.x, __float_as_int(w));
    }
}

// ---------------------------------------------------------------------------
// Weight pre-pack: conv_w (fp32 [k][col]) -> fp16 MFMA A-operand fragment
// order. For 16x16x32: lane (quad=l>>4, m=l&15) holds elem [m][quad*8+j].
// Stored per (layer, coltile c, kfrag f, lane): 8 contiguous halves.
// ---------------------------------------------------------------------------
__global__ void wpack_k(const float* __restrict__ conv_w, _Float16* __restrict__ bp) {
    int g = blockIdx.x * 256 + threadIdx.x;   // 3 * 2048
    if (g >= 3 * 2048) return;
    int l = g >> 11;
    int rem = g & 2047;
    int c = rem >> 8;
    int f = (rem >> 6) & 3;
    int lane = rem & 63;
    const float* W = conv_w + l * DIM * DIM;
    int kbase = f * 32 + (lane >> 4) * 8;
    int col = c * 16 + (lane & 15);
    _Float16* d = bp + ((size_t)l * 2048 + (size_t)(c * 4 + f) * 64 + lane) * 8;
#pragma unroll
    for (int j = 0; j < 8; ++j)
        d[j] = (_Float16)W[(kbase + j) * DIM + col];
}

// ---------------------------------------------------------------------------
// MFMA GEMM: T[n,128](fp16) = A[n,128] @ W ; fp32 accumulate in AGPR.
// Computes D^T via operand swap mfma(b_frag, a_frag, acc): lane then owns
// output row r0+m with 4 CONSECUTIVE cols per acc -> one 8B store per c-tile
// (a direct C-layout store would be 4x 2B scattered stores -> store-issue
// bound at ~80us for the whole op).
// block = 256 (4 waves); wave computes 16 rows x 128 cols; grid = ceil(n/64).
// ---------------------------------------------------------------------------
template <bool FP16IN>
__global__ __launch_bounds__(256) void gemm_k(const void* __restrict__ Ain,
                                              const _Float16* __restrict__ Bp,
                                              __half* __restrict__ T, int n) {
    const int lane = threadIdx.x & 63;
    const int wave = threadIdx.x >> 6;
    const int quad = lane >> 4;
    const int m    = lane & 15;
    const int row  = blockIdx.x * 64 + wave * 16 + m;
    const int rl   = row < n ? row : n - 1;

    half8 a[4];
    if (FP16IN) {
        const half8* A8 = (const half8*)((const _Float16*)Ain + (size_t)rl * DIM);
#pragma unroll
        for (int f = 0; f < 4; ++f) a[f] = A8[f * 4 + quad];
    } else {
        const float* A = (const float*)Ain + (size_t)rl * DIM;
#pragma unroll
        for (int f = 0; f < 4; ++f) {
            const float4* s4 = (const float4*)(A + f * 32 + quad * 8);
            float4 v0 = s4[0], v1 = s4[1];
            half8 v;
            v[0] = (_Float16)v0.x; v[1] = (_Float16)v0.y;
            v[2] = (_Float16)v0.z; v[3] = (_Float16)v0.w;
            v[4] = (_Float16)v1.x; v[5] = (_Float16)v1.y;
            v[6] = (_Float16)v1.z; v[7] = (_Float16)v1.w;
            a[f] = v;
        }
    }

    const half8* B8 = (const half8*)Bp;   // 32KB/layer, hot in L1
#pragma unroll
    for (int c = 0; c < 8; ++c) {
        f32x4 acc = {0.f, 0.f, 0.f, 0.f};
#pragma unroll
        for (int f = 0; f < 4; ++f) {
            half8 b = B8[(c * 4 + f) * 64 + lane];
            acc = __builtin_amdgcn_mfma_f32_16x16x32_f16(b, a[f], acc, 0, 0, 0);
        }
        if (row < n) {
            __half2 h01 = __floats2half2_rn(acc[0], acc[1]);
            __half2 h23 = __floats2half2_rn(acc[2], acc[3]);
            *(int2*)(T + (size_t)row * DIM + c * 16 + quad * 4) =
                make_int2(*(int*)&h01, *(int*)&h23);
        }
    }
}

// ---------------------------------------------------------------------------
// Aggregation: O[v] = relu( dis[v]^2 * T[v] + sum_e wgt[e]*T[col[e]] + b )
// one wave per node; fp16 in, fp32 accumulate, fp16 out. Unrolled 8/4 for MLP.
// Fetch-bound: dur ~= FETCH / 2.9 TB/s (random 256B row gather).
// ---------------------------------------------------------------------------
__global__ __launch_bounds__(256) void agg_k(const __half* __restrict__ T,
                                             const int* __restrict__ rowptr,
                                             const int2* __restrict__ ew,
                                             const float* __restrict__ dis,
                                             const float* __restrict__ bias,
                                             __half* __restrict__ O, int n) {
    int lane = threadIdx.x & 63;
    int v = blockIdx.x * 4 + (threadIdx.x >> 6);
    if (v >= n) return;

    const __half2* T2 = (const __half2*)T;  // 64 half2 per row
    float dv = dis[v];
    int e0 = rowptr[v], e1 = rowptr[v + 1];

    float2 t = __half22float2(T2[(size_t)v * 64 + lane]);
    float2 acc;
    acc.x = t.x * dv * dv;
    acc.y = t.y * dv * dv;

    int e = e0;
    for (; e + 8 <= e1; e += 8) {
        int2 p0 = ew[e + 0], p1 = ew[e + 1], p2 = ew[e + 2], p3 = ew[e + 3];
        int2 p4 = ew[e + 4], p5 = ew[e + 5], p6 = ew[e + 6], p7 = ew[e + 7];
        float2 u0 = __half22float2(T2[(size_t)p0.x * 64 + lane]);
        float2 u1 = __half22float2(T2[(size_t)p1.x * 64 + lane]);
        float2 u2 = __half22float2(T2[(size_t)p2.x * 64 + lane]);
        float2 u3 = __half22float2(T2[(size_t)p3.x * 64 + lane]);
        float2 u4 = __half22float2(T2[(size_t)p4.x * 64 + lane]);
        float2 u5 = __half22float2(T2[(size_t)p5.x * 64 + lane]);
        float2 u6 = __half22float2(T2[(size_t)p6.x * 64 + lane]);
        float2 u7 = __half22float2(T2[(size_t)p7.x * 64 + lane]);
        float w0 = __int_as_float(p0.y), w1 = __int_as_float(p1.y);
        float w2 = __int_as_float(p2.y), w3 = __int_as_float(p3.y);
        float w4 = __int_as_float(p4.y), w5 = __int_as_float(p5.y);
        float w6 = __int_as_float(p6.y), w7 = __int_as_float(p7.y);
        acc.x += w0 * u0.x; acc.y += w0 * u0.y;
        acc.x += w1 * u1.x; acc.y += w1 * u1.y;
        acc.x += w2 * u2.x; acc.y += w2 * u2.y;
        acc.x += w3 * u3.x; acc.y += w3 * u3.y;
        acc.x += w4 * u4.x; acc.y += w4 * u4.y;
        acc.x += w5 * u5.x; acc.y += w5 * u5.y;
        acc.x += w6 * u6.x; acc.y += w6 * u6.y;
        acc.x += w7 * u7.x; acc.y += w7 * u7.y;
    }
    for (; e + 4 <= e1; e += 4) {
        int2 p0 = ew[e + 0], p1 = ew[e + 1], p2 = ew[e + 2], p3 = ew[e + 3];
        float2 u0 = __half22float2(T2[(size_t)p0.x * 64 + lane]);
        float2 u1 = __half22float2(T2[(size_t)p1.x * 64 + lane]);
        float2 u2 = __half22float2(T2[(size_t)p2.x * 64 + lane]);
        float2 u3 = __half22float2(T2[(size_t)p3.x * 64 + lane]);
        float w0 = __int_as_float(p0.y), w1 = __int_as_float(p1.y);
        float w2 = __int_as_float(p2.y), w3 = __int_as_float(p3.y);
        acc.x += w0 * u0.x; acc.y += w0 * u0.y;
        acc.x += w1 * u1.x; acc.y += w1 * u1.y;
        acc.x += w2 * u2.x; acc.y += w2 * u2.y;
        acc.x += w3 * u3.x; acc.y += w3 * u3.y;
    }
    for (; e < e1; ++e) {
        int2 p = ew[e];
        float w = __int_as_float(p.y);
        float2 u = __half22float2(T2[(size_t)p.x * 64 + lane]);
        acc.x += w * u.x;
        acc.y += w * u.y;
    }

    float2 b = ((const float2*)bias)[lane];
    __half2 o = __floats2half2_rn(fmaxf(acc.x + b.x, 0.f), fmaxf(acc.y + b.y, 0.f));
    ((__half2*)O)[(size_t)v * 64 + lane] = o;
}

// ---------------------------------------------------------------------------
// Global mean pool (fp16 in, fp32 out), split-parallel: grid (n_graphs, POOL_SPLIT)
// ---------------------------------------------------------------------------
__global__ __launch_bounds__(64) void pool_k(const __half* __restrict__ H,
                                             const int* __restrict__ batch,
                                             float* __restrict__ G, int n) {
    int g = blockIdx.x;
    int part = blockIdx.y;

    int lo = 0, hi = n;
    while (lo < hi) { int m = (lo + hi) >> 1; if (batch[m] < g) lo = m + 1; else hi = m; }
    int start = lo;
    lo = start; hi = n;
    while (lo < hi) { int m = (lo + hi) >> 1; if (batch[m] < g + 1) lo = m + 1; else hi = m; }
    int end = lo;
    int cnt = end - start;
    if (cnt <= 0) return;
    float inv = 1.0f / (float)cnt;

    int lane = threadIdx.x;
    const __half2* H2 = (const __half2*)H;
    float2 s = make_float2(0.f, 0.f);
    for (int v = start + part; v < end; v += POOL_SPLIT) {
        float2 h = __half22float2(H2[(size_t)v * 64 + lane]);
        s.x += h.x; s.y += h.y;
    }
    atomicAdd(&G[g * DIM + 2 * lane + 0], s.x * inv);
    atomicAdd(&G[g * DIM + 2 * lane + 1], s.y * inv);
}

// ---------------------------------------------------------------------------
// Head: y = relu(g@lin1+b1); logits = y@lin2+b2; out = log_softmax(logits)
// ---------------------------------------------------------------------------
__global__ __launch_bounds__(128) void head_k(const float* __restrict__ G,
                                              const float* __restrict__ l1w,
                                              const float* __restrict__ l1b,
                                              const float* __restrict__ l2w,
                                              const float* __restrict__ l2b,
                                              float* __restrict__ out) {
    int g = blockIdx.x;
    int j = threadIdx.x;
    __shared__ float gs[128];
    __shared__ float2 red[128];

    gs[j] = G[g * 128 + j];
    __syncthreads();

    float acc = l1b[j];
    for (int k = 0; k < 128; ++k) acc += gs[k] * l1w[k * 128 + j];
    float y = fmaxf(acc, 0.f);

    red[j] = make_float2(y * l2w[j * 2 + 0], y * l2w[j * 2 + 1]);
    __syncthreads();
    for (int s = 64; s > 0; s >>= 1) {
        if (j < s) {
            red[j].x += red[j + s].x;
            red[j].y += red[j + s].y;
        }
        __syncthreads();
    }
    if (j == 0) {
        float l0 = red[0].x + l2b[0];
        float l1 = red[0].y + l2b[1];
        float m = fmaxf(l0, l1);
        float lse = m + logf(expf(l0 - m) + expf(l1 - m));
        out[g * 2 + 0] = l0 - lse;
        out[g * 2 + 1] = l1 - lse;
    }
}

// ---------------------------------------------------------------------------
// Launch
// ---------------------------------------------------------------------------
extern "C" void kernel_launch(void* const* d_in, const int* in_sizes, int n_in,
                              void* d_out, int out_size, void* d_ws, size_t ws_size,
                              hipStream_t stream) {
    const float* x       = (const float*)d_in[0];
    const int*   ei      = (const int*)d_in[1];
    const int*   batch   = (const int*)d_in[2];
    const float* conv_w  = (const float*)d_in[3];
    const float* conv_b  = (const float*)d_in[4];
    const float* lin1_w  = (const float*)d_in[5];
    const float* lin1_b  = (const float*)d_in[6];
    const float* lin2_w  = (const float*)d_in[7];
    const float* lin2_b  = (const float*)d_in[8];
    float* out = (float*)d_out;

    const int n = in_sizes[0] / DIM;      // 100000
    const int E = in_sizes[1] / 2;        // 1600000
    const int n_graphs = 128;
    const int NBIN = (n + (1 << BINSH) - 1) >> BINSH;   // 98 dst-bins

    const int* src = ei;
    const int* dst = ei + E;

    // workspace layout (all 256B aligned)
    char* p = (char*)d_ws;
    auto alloc = [&](size_t bytes) {
        char* r = p;
        p += (bytes + 255) & ~(size_t)255;
        return r;
    };
    __half*    bufH   = (__half*)alloc((size_t)n * DIM * 2);  // agg output (fp16)
    __half*    bufT   = (__half*)alloc((size_t)n * DIM * 2);  // gemm output (fp16)
    float*     dis    = (float*)alloc((size_t)n * 4);
    int*       counts = (int*)alloc((size_t)n * 4);
    int*       incl   = (int*)alloc((size_t)n * 4);
    int*       rowptr = (int*)alloc((size_t)(n + 1) * 4);
    int*       bsum   = (int*)alloc(512 * 4);
    int*       bincur = (int*)alloc((size_t)NBIN * 16 * 4);   // line-padded cursors
    int2*      tmp    = (int2*)alloc((size_t)E * 8);          // binned {src,dst}
    int2*      ew     = (int2*)alloc((size_t)E * 8);          // CSR {col, wgt}
    float*     gbuf   = (float*)alloc((size_t)n_graphs * DIM * 4);
    _Float16*  bp     = (_Float16*)alloc((size_t)3 * 2048 * 8 * 2);  // packed W frags
    (void)ws_size;

    const int nScanBlocks = (n + 255) / 256;        // 391 (<=512)
    const int eBlocks = (E + 255) / 256;
    const int binBlocks = (E + EPB - 1) / EPB;      // 98

    hipMemsetAsync(counts, 0, (size_t)n * 4, stream);
    hipMemsetAsync(gbuf, 0, (size_t)n_graphs * DIM * 4, stream);
    wpack_k<<<24, 256, 0, stream>>>(conv_w, bp);
    count_k<<<eBlocks, 256, 0, stream>>>(dst, counts, E);
    scan1_k<<<nScanBlocks, 256, 0, stream>>>(counts, incl, bsum, n);
    scan2_k<<<1, 512, 0, stream>>>(bsum, nScanBlocks);
    scan3_k<<<nScanBlocks, 256, 0, stream>>>(counts, incl, bsum, rowptr, dis, n, E);
    binscan_k<<<(NBIN + 255) / 256, 256, 0, stream>>>(rowptr, bincur, NBIN);
    bin_k<<<binBlocks, 256, 0, stream>>>(src, dst, bincur, tmp, E, NBIN);
    fill2_k<<<NBIN, 256, 0, stream>>>(tmp, rowptr, dis, ew, n);

    const int gemmBlocks = (n + 63) / 64;
    const int aggBlocks = (n + 3) / 4;

    // layer 0: x (fp32) -> bufT -> bufH
    gemm_k<false><<<gemmBlocks, 256, 0, stream>>>((const void*)x, bp + 0 * 16384, bufT, n);
    agg_k<<<aggBlocks, 256, 0, stream>>>(bufT, rowptr, ew, dis, conv_b + 0 * DIM, bufH, n);
    // layer 1
    gemm_k<true><<<gemmBlocks, 256, 0, stream>>>((const void*)bufH, bp + 1 * 16384, bufT, n);
    agg_k<<<aggBlocks, 256, 0, stream>>>(bufT, rowptr, ew, dis, conv_b + 1 * DIM, bufH, n);
    // layer 2
    gemm_k<true><<<gemmBlocks, 256, 0, stream>>>((const void*)bufH, bp + 2 * 16384, bufT, n);
    agg_k<<<aggBlocks, 256, 0, stream>>>(bufT, rowptr, ew, dis, conv_b + 2 * DIM, bufH, n);

    dim3 pgrid(n_graphs, POOL_SPLIT);
    pool_k<<<pgrid, 64, 0, stream>>>(bufH, batch, gbuf, n);
    head_k<<<n_graphs, 128, 0, stream>>>(gbuf, lin1_w, lin1_b, lin2_w, lin2_b, out);
}

// Round 9
// 497.740 us; speedup vs baseline: 1.7229x; 1.0782x over previous
//
#include <hip/hip_runtime.h>
#include <hip/hip_fp16.h>
#include <math.h>

#define DIM 128
#define POOL_SPLIT 32  // partial-sum blocks per graph
#define BINSH 10       // 1024 nodes per dst-bin
#define EPB 16384      // edges per bin_k block
// Build discipline learned R6: per-EDGE global atomics ping-pong cache lines
// across the 8 non-coherent XCD L2s (~50ns/bounce) — catastrophic. All
// per-edge counting happens in LDS; global atomics only per (block,bin),
// issued as one burst per block so line ownership is acquired once per block.

typedef __attribute__((ext_vector_type(8))) _Float16 half8;
typedef __attribute__((ext_vector_type(4))) float f32x4;

// ---------------------------------------------------------------------------
// Graph build: bincount -> binscan -> bin (scatter to bin-ordered tmp)
//              -> rowcnt (per-node deg/rowptr/dis from tmp, LDS only)
//              -> fill2 (place {src,wgt} into CSR)
// ---------------------------------------------------------------------------

// LDS histogram over dst bins; one global atomic per (block,bin)
__global__ __launch_bounds__(256) void bincount_k(const int* __restrict__ dst,
                                                  int* __restrict__ binsize,
                                                  int E, int NBIN) {
    __shared__ int h[128];
    const int t = threadIdx.x;
    if (t < 128) h[t] = 0;
    __syncthreads();
    const int e0 = blockIdx.x * EPB;
    const int e1 = min(e0 + EPB, E);
    for (int e = e0 + t; e < e1; e += 256)
        atomicAdd(&h[dst[e] >> BINSH], 1);
    __syncthreads();
    if (t < NBIN && h[t]) atomicAdd(&binsize[t], h[t]);
}

// single block: exclusive scan of binsize -> binbase; init line-padded bincur
__global__ void binscan2_k(const int* __restrict__ binsize, int* __restrict__ binbase,
                           int* __restrict__ bincur, int NBIN, int E) {
    __shared__ int s[128];
    const int t = threadIdx.x;   // 128 threads
    int v = (t < NBIN) ? binsize[t] : 0;
    s[t] = v;
    __syncthreads();
    for (int off = 1; off < 128; off <<= 1) {
        int u = (t >= off) ? s[t - off] : 0;
        __syncthreads();
        s[t] += u;
        __syncthreads();
    }
    int excl = s[t] - v;
    if (t < NBIN) { binbase[t] = excl; bincur[t * 16] = excl; }
    if (t == 0) binbase[NBIN] = E;
}

// bin edges by dst>>BINSH: LDS histogram -> 1 reservation atomic per
// (block,bin) -> contiguous per-block runs => writes merge in this CU's L2.
__global__ __launch_bounds__(256) void bin_k(const int* __restrict__ src,
                                             const int* __restrict__ dst,
                                             int* __restrict__ bincur,
                                             int2* __restrict__ tmp, int E, int NBIN) {
    __shared__ int cur[128];
    const int t = threadIdx.x;
    if (t < 128) cur[t] = 0;
    __syncthreads();
    const int e0 = blockIdx.x * EPB;
    const int e1 = min(e0 + EPB, E);
    for (int e = e0 + t; e < e1; e += 256)
        atomicAdd(&cur[dst[e] >> BINSH], 1);
    __syncthreads();
    if (t < NBIN) {
        int h = cur[t];
        cur[t] = h ? atomicAdd(&bincur[t * 16], h) : 0;
    }
    __syncthreads();
    for (int e = e0 + t; e < e1; e += 256) {
        int d = dst[e], s = src[e];
        int pos = atomicAdd(&cur[d >> BINSH], 1);
        tmp[pos] = make_int2(s, d);
    }
}

// one block per bin: per-node degree count in LDS from tmp, LDS prefix scan
// -> rowptr (global CSR offsets) + dis = rsqrt(deg+1). No global atomics.
__global__ __launch_bounds__(256) void rowcnt_k(const int2* __restrict__ tmp,
                                                const int* __restrict__ binbase,
                                                int* __restrict__ rowptr,
                                                float* __restrict__ dis,
                                                int n, int E, int NBIN) {
    __shared__ int cnt[1 << BINSH];
    __shared__ int part[256];
    const int b = blockIdx.x, t = threadIdx.x;
    for (int i = t; i < (1 << BINSH); i += 256) cnt[i] = 0;
    __syncthreads();
    const int ebeg = binbase[b], eend = binbase[b + 1];
    for (int e = ebeg + t; e < eend; e += 256)
        atomicAdd(&cnt[tmp[e].y & ((1 << BINSH) - 1)], 1);
    __syncthreads();
    int cc[4];
    cc[0] = cnt[t * 4 + 0]; cc[1] = cnt[t * 4 + 1];
    cc[2] = cnt[t * 4 + 2]; cc[3] = cnt[t * 4 + 3];
    int s = cc[0] + cc[1] + cc[2] + cc[3];
    part[t] = s;
    __syncthreads();
    for (int off = 1; off < 256; off <<= 1) {
        int u = (t >= off) ? part[t - off] : 0;
        __syncthreads();
        part[t] += u;
        __syncthreads();
    }
    int off0 = ebeg + part[t] - s;   // exclusive offset of this thread's 4 nodes
    int node0 = (b << BINSH) + t * 4;
    int pre = 0;
#pragma unroll
    for (int j = 0; j < 4; ++j) {
        int node = node0 + j;
        if (node < n) {
            rowptr[node] = off0 + pre;
            dis[node] = rsqrtf((float)(cc[j] + 1));
        }
        pre += cc[j];
    }
    if (b == NBIN - 1 && t == 0) rowptr[n] = E;
}

// one block per bin; LDS per-node cursors; place {src,wgt} into the
// bin's ~130KB CSR region (single-XCD writes -> full line merge).
__global__ __launch_bounds__(256) void fill2_k(const int2* __restrict__ tmp,
                                               const int* __restrict__ rowptr,
                                               const float* __restrict__ dis,
                                               int2* __restrict__ ew, int n) {
    __shared__ int lcur[1 << BINSH];
    const int base_node = blockIdx.x << BINSH;
    const int t = threadIdx.x;
    for (int i = t; i < (1 << BINSH); i += 256)
        if (base_node + i < n) lcur[i] = rowptr[base_node + i];
    const int e_begin = rowptr[base_node];
    const int e_end   = rowptr[min(base_node + (1 << BINSH), n)];
    __syncthreads();
    for (int e = e_begin + t; e < e_end; e += 256) {
        int2 r = tmp[e];
        float w = dis[r.x] * dis[r.y];
        int q = atomicAdd(&lcur[r.y & ((1 << BINSH) - 1)], 1);
        ew[q] = make_int2(r.x, __float_as_int(w));
    }
}

// ---------------------------------------------------------------------------
// Weight pre-pack: conv_w (fp32 [k][col]) -> fp16 MFMA A-operand fragment
// order. For 16x16x32: lane (quad=l>>4, m=l&15) holds elem [m][quad*8+j].
// ---------------------------------------------------------------------------
__global__ void wpack_k(const float* __restrict__ conv_w, _Float16* __restrict__ bp) {
    int g = blockIdx.x * 256 + threadIdx.x;   // 3 * 2048
    if (g >= 3 * 2048) return;
    int l = g >> 11;
    int rem = g & 2047;
    int c = rem >> 8;
    int f = (rem >> 6) & 3;
    int lane = rem & 63;
    const float* W = conv_w + l * DIM * DIM;
    int kbase = f * 32 + (lane >> 4) * 8;
    int col = c * 16 + (lane & 15);
    _Float16* d = bp + ((size_t)l * 2048 + (size_t)(c * 4 + f) * 64 + lane) * 8;
#pragma unroll
    for (int j = 0; j < 8; ++j)
        d[j] = (_Float16)W[(kbase + j) * DIM + col];
}

// ---------------------------------------------------------------------------
// MFMA GEMM: T[n,128](fp16) = A[n,128] @ W ; fp32 accumulate. D^T via operand
// swap mfma(b,a,acc) -> lane owns 4 consecutive cols of one row -> 8B stores.
// ---------------------------------------------------------------------------
template <bool FP16IN>
__global__ __launch_bounds__(256) void gemm_k(const void* __restrict__ Ain,
                                              const _Float16* __restrict__ Bp,
                                              __half* __restrict__ T, int n) {
    const int lane = threadIdx.x & 63;
    const int wave = threadIdx.x >> 6;
    const int quad = lane >> 4;
    const int m    = lane & 15;
    const int row  = blockIdx.x * 64 + wave * 16 + m;
    const int rl   = row < n ? row : n - 1;

    half8 a[4];
    if (FP16IN) {
        const half8* A8 = (const half8*)((const _Float16*)Ain + (size_t)rl * DIM);
#pragma unroll
        for (int f = 0; f < 4; ++f) a[f] = A8[f * 4 + quad];
    } else {
        const float* A = (const float*)Ain + (size_t)rl * DIM;
#pragma unroll
        for (int f = 0; f < 4; ++f) {
            const float4* s4 = (const float4*)(A + f * 32 + quad * 8);
            float4 v0 = s4[0], v1 = s4[1];
            half8 v;
            v[0] = (_Float16)v0.x; v[1] = (_Float16)v0.y;
            v[2] = (_Float16)v0.z; v[3] = (_Float16)v0.w;
            v[4] = (_Float16)v1.x; v[5] = (_Float16)v1.y;
            v[6] = (_Float16)v1.z; v[7] = (_Float16)v1.w;
            a[f] = v;
        }
    }

    const half8* B8 = (const half8*)Bp;   // 32KB/layer, hot in L1
#pragma unroll
    for (int c = 0; c < 8; ++c) {
        f32x4 acc = {0.f, 0.f, 0.f, 0.f};
#pragma unroll
        for (int f = 0; f < 4; ++f) {
            half8 b = B8[(c * 4 + f) * 64 + lane];
            acc = __builtin_amdgcn_mfma_f32_16x16x32_f16(b, a[f], acc, 0, 0, 0);
        }
        if (row < n) {
            __half2 h01 = __floats2half2_rn(acc[0], acc[1]);
            __half2 h23 = __floats2half2_rn(acc[2], acc[3]);
            *(int2*)(T + (size_t)row * DIM + c * 16 + quad * 4) =
                make_int2(*(int*)&h01, *(int*)&h23);
        }
    }
}

// ---------------------------------------------------------------------------
// Aggregation: O[v] = relu( dis[v]^2 * T[v] + sum_e wgt[e]*T[col[e]] + b )
// one wave per node; fp16 in, fp32 accumulate, fp16 out. Unrolled 16/8/4 for
// memory-level parallelism (raw half2 staged, converted after loads issue).
// ---------------------------------------------------------------------------
__global__ __launch_bounds__(256) void agg_k(const __half* __restrict__ T,
                                             const int* __restrict__ rowptr,
                                             const int2* __restrict__ ew,
                                             const float* __restrict__ dis,
                                             const float* __restrict__ bias,
                                             __half* __restrict__ O, int n) {
    int lane = threadIdx.x & 63;
    int v = blockIdx.x * 4 + (threadIdx.x >> 6);
    if (v >= n) return;

    const __half2* T2 = (const __half2*)T;  // 64 half2 per row
    float dv = dis[v];
    int e0 = rowptr[v], e1 = rowptr[v + 1];

    float2 t = __half22float2(T2[(size_t)v * 64 + lane]);
    float2 acc;
    acc.x = t.x * dv * dv;
    acc.y = t.y * dv * dv;

    int e = e0;
    {
        int2 pp[16];
        __half2 uh[16];
        for (; e + 16 <= e1; e += 16) {
#pragma unroll
            for (int j = 0; j < 16; ++j) pp[j] = ew[e + j];
#pragma unroll
            for (int j = 0; j < 16; ++j) uh[j] = T2[(size_t)pp[j].x * 64 + lane];
#pragma unroll
            for (int j = 0; j < 16; ++j) {
                float2 u = __half22float2(uh[j]);
                float w = __int_as_float(pp[j].y);
                acc.x += w * u.x; acc.y += w * u.y;
            }
        }
        for (; e + 8 <= e1; e += 8) {
#pragma unroll
            for (int j = 0; j < 8; ++j) pp[j] = ew[e + j];
#pragma unroll
            for (int j = 0; j < 8; ++j) uh[j] = T2[(size_t)pp[j].x * 64 + lane];
#pragma unroll
            for (int j = 0; j < 8; ++j) {
                float2 u = __half22float2(uh[j]);
                float w = __int_as_float(pp[j].y);
                acc.x += w * u.x; acc.y += w * u.y;
            }
        }
        for (; e + 4 <= e1; e += 4) {
#pragma unroll
            for (int j = 0; j < 4; ++j) pp[j] = ew[e + j];
#pragma unroll
            for (int j = 0; j < 4; ++j) uh[j] = T2[(size_t)pp[j].x * 64 + lane];
#pragma unroll
            for (int j = 0; j < 4; ++j) {
                float2 u = __half22float2(uh[j]);
                float w = __int_as_float(pp[j].y);
                acc.x += w * u.x; acc.y += w * u.y;
            }
        }
    }
    for (; e < e1; ++e) {
        int2 p = ew[e];
        float w = __int_as_float(p.y);
        float2 u = __half22float2(T2[(size_t)p.x * 64 + lane]);
        acc.x += w * u.x;
        acc.y += w * u.y;
    }

    float2 b = ((const float2*)bias)[lane];
    __half2 o = __floats2half2_rn(fmaxf(acc.x + b.x, 0.f), fmaxf(acc.y + b.y, 0.f));
    ((__half2*)O)[(size_t)v * 64 + lane] = o;
}

// ---------------------------------------------------------------------------
// Global mean pool (fp16 in, fp32 out), split-parallel: grid (n_graphs, POOL_SPLIT)
// ---------------------------------------------------------------------------
__global__ __launch_bounds__(64) void pool_k(const __half* __restrict__ H,
                                             const int* __restrict__ batch,
                                             float* __restrict__ G, int n) {
    int g = blockIdx.x;
    int part = blockIdx.y;

    int lo = 0, hi = n;
    while (lo < hi) { int m = (lo + hi) >> 1; if (batch[m] < g) lo = m + 1; else hi = m; }
    int start = lo;
    lo = start; hi = n;
    while (lo < hi) { int m = (lo + hi) >> 1; if (batch[m] < g + 1) lo = m + 1; else hi = m; }
    int end = lo;
    int cnt = end - start;
    if (cnt <= 0) return;
    float inv = 1.0f / (float)cnt;

    int lane = threadIdx.x;
    const __half2* H2 = (const __half2*)H;
    float2 s = make_float2(0.f, 0.f);
    for (int v = start + part; v < end; v += POOL_SPLIT) {
        float2 h = __half22float2(H2[(size_t)v * 64 + lane]);
        s.x += h.x; s.y += h.y;
    }
    atomicAdd(&G[g * DIM + 2 * lane + 0], s.x * inv);
    atomicAdd(&G[g * DIM + 2 * lane + 1], s.y * inv);
}

// ---------------------------------------------------------------------------
// Head: y = relu(g@lin1+b1); logits = y@lin2+b2; out = log_softmax(logits)
// ---------------------------------------------------------------------------
__global__ __launch_bounds__(128) void head_k(const float* __restrict__ G,
                                              const float* __restrict__ l1w,
                                              const float* __restrict__ l1b,
                                              const float* __restrict__ l2w,
                                              const float* __restrict__ l2b,
                                              float* __restrict__ out) {
    int g = blockIdx.x;
    int j = threadIdx.x;
    __shared__ float gs[128];
    __shared__ float2 red[128];

    gs[j] = G[g * 128 + j];
    __syncthreads();

    float acc = l1b[j];
    for (int k = 0; k < 128; ++k) acc += gs[k] * l1w[k * 128 + j];
    float y = fmaxf(acc, 0.f);

    red[j] = make_float2(y * l2w[j * 2 + 0], y * l2w[j * 2 + 1]);
    __syncthreads();
    for (int s = 64; s > 0; s >>= 1) {
        if (j < s) {
            red[j].x += red[j + s].x;
            red[j].y += red[j + s].y;
        }
        __syncthreads();
    }
    if (j == 0) {
        float l0 = red[0].x + l2b[0];
        float l1 = red[0].y + l2b[1];
        float m = fmaxf(l0, l1);
        float lse = m + logf(expf(l0 - m) + expf(l1 - m));
        out[g * 2 + 0] = l0 - lse;
        out[g * 2 + 1] = l1 - lse;
    }
}

// ---------------------------------------------------------------------------
// Launch
// ---------------------------------------------------------------------------
extern "C" void kernel_launch(void* const* d_in, const int* in_sizes, int n_in,
                              void* d_out, int out_size, void* d_ws, size_t ws_size,
                              hipStream_t stream) {
    const float* x       = (const float*)d_in[0];
    const int*   ei      = (const int*)d_in[1];
    const int*   batch   = (const int*)d_in[2];
    const float* conv_w  = (const float*)d_in[3];
    const float* conv_b  = (const float*)d_in[4];
    const float* lin1_w  = (const float*)d_in[5];
    const float* lin1_b  = (const float*)d_in[6];
    const float* lin2_w  = (const float*)d_in[7];
    const float* lin2_b  = (const float*)d_in[8];
    float* out = (float*)d_out;

    const int n = in_sizes[0] / DIM;      // 100000
    const int E = in_sizes[1] / 2;        // 1600000
    const int n_graphs = 128;
    const int NBIN = (n + (1 << BINSH) - 1) >> BINSH;   // 98 dst-bins

    const int* src = ei;
    const int* dst = ei + E;

    // workspace layout (all 256B aligned)
    char* p = (char*)d_ws;
    auto alloc = [&](size_t bytes) {
        char* r = p;
        p += (bytes + 255) & ~(size_t)255;
        return r;
    };
    __half*    bufH    = (__half*)alloc((size_t)n * DIM * 2);  // agg output (fp16)
    __half*    bufT    = (__half*)alloc((size_t)n * DIM * 2);  // gemm output (fp16)
    float*     dis     = (float*)alloc((size_t)n * 4);
    int*       rowptr  = (int*)alloc((size_t)(n + 1) * 4);
    int*       binsize = (int*)alloc(128 * 4);
    int*       binbase = (int*)alloc(132 * 4);
    int*       bincur  = (int*)alloc((size_t)NBIN * 16 * 4);   // line-padded cursors
    int2*      tmp     = (int2*)alloc((size_t)E * 8);          // binned {src,dst}
    int2*      ew      = (int2*)alloc((size_t)E * 8);          // CSR {col, wgt}
    float*     gbuf    = (float*)alloc((size_t)n_graphs * DIM * 4);
    _Float16*  bp      = (_Float16*)alloc((size_t)3 * 2048 * 8 * 2);  // packed W frags
    (void)ws_size;

    const int binBlocks = (E + EPB - 1) / EPB;      // 98

    hipMemsetAsync(binsize, 0, 128 * 4, stream);
    hipMemsetAsync(gbuf, 0, (size_t)n_graphs * DIM * 4, stream);
    wpack_k<<<24, 256, 0, stream>>>(conv_w, bp);
    bincount_k<<<binBlocks, 256, 0, stream>>>(dst, binsize, E, NBIN);
    binscan2_k<<<1, 128, 0, stream>>>(binsize, binbase, bincur, NBIN, E);
    bin_k<<<binBlocks, 256, 0, stream>>>(src, dst, bincur, tmp, E, NBIN);
    rowcnt_k<<<NBIN, 256, 0, stream>>>(tmp, binbase, rowptr, dis, n, E, NBIN);
    fill2_k<<<NBIN, 256, 0, stream>>>(tmp, rowptr, dis, ew, n);

    const int gemmBlocks = (n + 63) / 64;
    const int aggBlocks = (n + 3) / 4;

    // layer 0: x (fp32) -> bufT -> bufH
    gemm_k<false><<<gemmBlocks, 256, 0, stream>>>((const void*)x, bp + 0 * 16384, bufT, n);
    agg_k<<<aggBlocks, 256, 0, stream>>>(bufT, rowptr, ew, dis, conv_b + 0 * DIM, bufH, n);
    // layer 1
    gemm_k<true><<<gemmBlocks, 256, 0, stream>>>((const void*)bufH, bp + 1 * 16384, bufT, n);
    agg_k<<<aggBlocks, 256, 0, stream>>>(bufT, rowptr, ew, dis, conv_b + 1 * DIM, bufH, n);
    // layer 2
    gemm_k<true><<<gemmBlocks, 256, 0, stream>>>((const void*)bufH, bp + 2 * 16384, bufT, n);
    agg_k<<<aggBlocks, 256, 0, stream>>>(bufT, rowptr, ew, dis, conv_b + 2 * DIM, bufH, n);

    dim3 pgrid(n_graphs, POOL_SPLIT);
    pool_k<<<pgrid, 64, 0, stream>>>(bufH, batch, gbuf, n);
    head_k<<<n_graphs, 128, 0, stream>>>(gbuf, lin1_w, lin1_b, lin2_w, lin2_b, out);
}

// Round 10
// 492.738 us; speedup vs baseline: 1.7404x; 1.0102x over previous
//
#include <hip/hip_runtime.h>
#include <hip/hip_fp16.h>
#include <math.h>

#define DIM 128
#define POOL_SPLIT 32  // partial-sum blocks per graph
#define BINSH 10       // 1024 nodes per dst-bin
#define EPB 16384      // edges per bin_k block
#define ALH 136        // gemm A-tile LDS row stride in halves (272B): ds_read_b128
                       // start banks = 4*((m+quad)&7) -> all 8 groups, no conflict
// Build discipline learned R6: per-EDGE global atomics ping-pong cache lines
// across the 8 non-coherent XCD L2s (~50ns/bounce) — catastrophic. All
// per-edge counting happens in LDS; global atomics only per (block,bin).
// Agg discipline learned R9: >8-wide unroll trades occupancy for MLP at a net
// loss; 8/4 unroll + VGPR<=32 is the measured sweet spot (68.0us).

typedef __attribute__((ext_vector_type(8))) _Float16 half8;
typedef __attribute__((ext_vector_type(4))) float f32x4;

// ---------------------------------------------------------------------------
// Graph build: bincount -> binscan -> bin (scatter to bin-ordered tmp)
//              -> rowcnt (per-node deg/rowptr/dis from tmp, LDS only)
//              -> fill2 (place {src,wgt} into CSR)
// ---------------------------------------------------------------------------

// LDS histogram over dst bins; one global atomic per (block,bin)
__global__ __launch_bounds__(256) void bincount_k(const int* __restrict__ dst,
                                                  int* __restrict__ binsize,
                                                  int E, int NBIN) {
    __shared__ int h[128];
    const int t = threadIdx.x;
    if (t < 128) h[t] = 0;
    __syncthreads();
    const int e0 = blockIdx.x * EPB;
    const int e1 = min(e0 + EPB, E);
    for (int e = e0 + t; e < e1; e += 256)
        atomicAdd(&h[dst[e] >> BINSH], 1);
    __syncthreads();
    if (t < NBIN && h[t]) atomicAdd(&binsize[t], h[t]);
}

// single block: exclusive scan of binsize -> binbase; init line-padded bincur
__global__ void binscan2_k(const int* __restrict__ binsize, int* __restrict__ binbase,
                           int* __restrict__ bincur, int NBIN, int E) {
    __shared__ int s[128];
    const int t = threadIdx.x;   // 128 threads
    int v = (t < NBIN) ? binsize[t] : 0;
    s[t] = v;
    __syncthreads();
    for (int off = 1; off < 128; off <<= 1) {
        int u = (t >= off) ? s[t - off] : 0;
        __syncthreads();
        s[t] += u;
        __syncthreads();
    }
    int excl = s[t] - v;
    if (t < NBIN) { binbase[t] = excl; bincur[t * 16] = excl; }
    if (t == 0) binbase[NBIN] = E;
}

// bin edges by dst>>BINSH: LDS histogram -> 1 reservation atomic per
// (block,bin) -> contiguous per-block runs => writes merge in this CU's L2.
__global__ __launch_bounds__(256) void bin_k(const int* __restrict__ src,
                                             const int* __restrict__ dst,
                                             int* __restrict__ bincur,
                                             int2* __restrict__ tmp, int E, int NBIN) {
    __shared__ int cur[128];
    const int t = threadIdx.x;
    if (t < 128) cur[t] = 0;
    __syncthreads();
    const int e0 = blockIdx.x * EPB;
    const int e1 = min(e0 + EPB, E);
    for (int e = e0 + t; e < e1; e += 256)
        atomicAdd(&cur[dst[e] >> BINSH], 1);
    __syncthreads();
    if (t < NBIN) {
        int h = cur[t];
        cur[t] = h ? atomicAdd(&bincur[t * 16], h) : 0;
    }
    __syncthreads();
    for (int e = e0 + t; e < e1; e += 256) {
        int d = dst[e], s = src[e];
        int pos = atomicAdd(&cur[d >> BINSH], 1);
        tmp[pos] = make_int2(s, d);
    }
}

// one block per bin: per-node degree count in LDS from tmp, LDS prefix scan
// -> rowptr (global CSR offsets) + dis = rsqrt(deg+1). No global atomics.
__global__ __launch_bounds__(256) void rowcnt_k(const int2* __restrict__ tmp,
                                                const int* __restrict__ binbase,
                                                int* __restrict__ rowptr,
                                                float* __restrict__ dis,
                                                int n, int E, int NBIN) {
    __shared__ int cnt[1 << BINSH];
    __shared__ int part[256];
    const int b = blockIdx.x, t = threadIdx.x;
    for (int i = t; i < (1 << BINSH); i += 256) cnt[i] = 0;
    __syncthreads();
    const int ebeg = binbase[b], eend = binbase[b + 1];
    for (int e = ebeg + t; e < eend; e += 256)
        atomicAdd(&cnt[tmp[e].y & ((1 << BINSH) - 1)], 1);
    __syncthreads();
    int cc[4];
    cc[0] = cnt[t * 4 + 0]; cc[1] = cnt[t * 4 + 1];
    cc[2] = cnt[t * 4 + 2]; cc[3] = cnt[t * 4 + 3];
    int s = cc[0] + cc[1] + cc[2] + cc[3];
    part[t] = s;
    __syncthreads();
    for (int off = 1; off < 256; off <<= 1) {
        int u = (t >= off) ? part[t - off] : 0;
        __syncthreads();
        part[t] += u;
        __syncthreads();
    }
    int off0 = ebeg + part[t] - s;   // exclusive offset of this thread's 4 nodes
    int node0 = (b << BINSH) + t * 4;
    int pre = 0;
#pragma unroll
    for (int j = 0; j < 4; ++j) {
        int node = node0 + j;
        if (node < n) {
            rowptr[node] = off0 + pre;
            dis[node] = rsqrtf((float)(cc[j] + 1));
        }
        pre += cc[j];
    }
    if (b == NBIN - 1 && t == 0) rowptr[n] = E;
}

// one block per bin; LDS per-node cursors; place {src,wgt} into the
// bin's ~130KB CSR region (single-XCD writes -> full line merge).
__global__ __launch_bounds__(256) void fill2_k(const int2* __restrict__ tmp,
                                               const int* __restrict__ rowptr,
                                               const float* __restrict__ dis,
                                               int2* __restrict__ ew, int n) {
    __shared__ int lcur[1 << BINSH];
    const int base_node = blockIdx.x << BINSH;
    const int t = threadIdx.x;
    for (int i = t; i < (1 << BINSH); i += 256)
        if (base_node + i < n) lcur[i] = rowptr[base_node + i];
    const int e_begin = rowptr[base_node];
    const int e_end   = rowptr[min(base_node + (1 << BINSH), n)];
    __syncthreads();
    for (int e = e_begin + t; e < e_end; e += 256) {
        int2 r = tmp[e];
        float w = dis[r.x] * dis[r.y];
        int q = atomicAdd(&lcur[r.y & ((1 << BINSH) - 1)], 1);
        ew[q] = make_int2(r.x, __float_as_int(w));
    }
}

// ---------------------------------------------------------------------------
// Weight pre-pack: conv_w (fp32 [k][col]) -> fp16 MFMA A-operand fragment
// order. For 16x16x32: lane (quad=l>>4, m=l&15) holds elem [m][quad*8+j].
// ---------------------------------------------------------------------------
__global__ void wpack_k(const float* __restrict__ conv_w, _Float16* __restrict__ bp) {
    int g = blockIdx.x * 256 + threadIdx.x;   // 3 * 2048
    if (g >= 3 * 2048) return;
    int l = g >> 11;
    int rem = g & 2047;
    int c = rem >> 8;
    int f = (rem >> 6) & 3;
    int lane = rem & 63;
    const float* W = conv_w + l * DIM * DIM;
    int kbase = f * 32 + (lane >> 4) * 8;
    int col = c * 16 + (lane & 15);
    _Float16* d = bp + ((size_t)l * 2048 + (size_t)(c * 4 + f) * 64 + lane) * 8;
#pragma unroll
    for (int j = 0; j < 8; ++j)
        d[j] = (_Float16)W[(kbase + j) * DIM + col];
}

// ---------------------------------------------------------------------------
// MFMA GEMM: T[n,128](fp16) = A[n,128] @ W ; fp32 accumulate. D^T via operand
// swap mfma(b,a,acc) -> lane owns 4 consecutive cols of one row -> 8B stores.
// A staged through LDS with COALESCED global loads (direct per-lane fragment
// loads touch 64 lines/wave using 16B of each = 4x over-fetch — R9 lesson).
// ---------------------------------------------------------------------------
template <bool FP16IN>
__global__ __launch_bounds__(256) void gemm_k(const void* __restrict__ Ain,
                                              const _Float16* __restrict__ Bp,
                                              __half* __restrict__ T, int n) {
    __shared__ _Float16 Al[64 * ALH];
    const int t = threadIdx.x;
    const int r0 = blockIdx.x * 64;
    const int nrows = min(64, n - r0);

    if (FP16IN) {
        const _Float16* A = (const _Float16*)Ain;
        // 64 rows x 16 chunks of 16B; consecutive t -> consecutive chunks
        for (int idx = t; idx < 64 * 16; idx += 256) {
            int row = idx >> 4, c = idx & 15;
            half8 v = {};
            if (row < nrows) v = *(const half8*)(A + (size_t)(r0 + row) * DIM + c * 8);
            *(half8*)&Al[row * ALH + c * 8] = v;
        }
    } else {
        const float* A = (const float*)Ain;
        // 64 rows x 32 chunks of 16B fp32 -> 8B fp16 LDS
        for (int idx = t; idx < 64 * 32; idx += 256) {
            int row = idx >> 5, c = idx & 31;
            float4 v = make_float4(0.f, 0.f, 0.f, 0.f);
            if (row < nrows) v = ((const float4*)(A + (size_t)(r0 + row) * DIM))[c];
            __half2 h01 = __floats2half2_rn(v.x, v.y);
            __half2 h23 = __floats2half2_rn(v.z, v.w);
            *(int2*)&Al[row * ALH + c * 4] = make_int2(*(int*)&h01, *(int*)&h23);
        }
    }
    __syncthreads();

    const int lane = t & 63;
    const int wave = t >> 6;
    const int quad = lane >> 4;
    const int m    = lane & 15;
    const int lrow = wave * 16 + m;
    const int row  = r0 + lrow;

    half8 a[4];
#pragma unroll
    for (int f = 0; f < 4; ++f)
        a[f] = *(const half8*)&Al[lrow * ALH + f * 32 + quad * 8];

    const half8* B8 = (const half8*)Bp;   // 32KB/layer, hot in L1
#pragma unroll
    for (int c = 0; c < 8; ++c) {
        f32x4 acc = {0.f, 0.f, 0.f, 0.f};
#pragma unroll
        for (int f = 0; f < 4; ++f) {
            half8 b = B8[(c * 4 + f) * 64 + lane];
            acc = __builtin_amdgcn_mfma_f32_16x16x32_f16(b, a[f], acc, 0, 0, 0);
        }
        if (row < n) {
            __half2 h01 = __floats2half2_rn(acc[0], acc[1]);
            __half2 h23 = __floats2half2_rn(acc[2], acc[3]);
            *(int2*)(T + (size_t)row * DIM + c * 16 + quad * 4) =
                make_int2(*(int*)&h01, *(int*)&h23);
        }
    }
}

// ---------------------------------------------------------------------------
// Aggregation: O[v] = relu( dis[v]^2 * T[v] + sum_e wgt[e]*T[col[e]] + b )
// one wave per node; fp16 in, fp32 accumulate, fp16 out. Unrolled 8/4 (R8
// measured optimum: VGPR 28, 68.0us; 16-wide regressed via occupancy).
// ---------------------------------------------------------------------------
__global__ __launch_bounds__(256) void agg_k(const __half* __restrict__ T,
                                             const int* __restrict__ rowptr,
                                             const int2* __restrict__ ew,
                                             const float* __restrict__ dis,
                                             const float* __restrict__ bias,
                                             __half* __restrict__ O, int n) {
    int lane = threadIdx.x & 63;
    int v = blockIdx.x * 4 + (threadIdx.x >> 6);
    if (v >= n) return;

    const __half2* T2 = (const __half2*)T;  // 64 half2 per row
    float dv = dis[v];
    int e0 = rowptr[v], e1 = rowptr[v + 1];

    float2 t = __half22float2(T2[(size_t)v * 64 + lane]);
    float2 acc;
    acc.x = t.x * dv * dv;
    acc.y = t.y * dv * dv;

    int e = e0;
    for (; e + 8 <= e1; e += 8) {
        int2 p0 = ew[e + 0], p1 = ew[e + 1], p2 = ew[e + 2], p3 = ew[e + 3];
        int2 p4 = ew[e + 4], p5 = ew[e + 5], p6 = ew[e + 6], p7 = ew[e + 7];
        float2 u0 = __half22float2(T2[(size_t)p0.x * 64 + lane]);
        float2 u1 = __half22float2(T2[(size_t)p1.x * 64 + lane]);
        float2 u2 = __half22float2(T2[(size_t)p2.x * 64 + lane]);
        float2 u3 = __half22float2(T2[(size_t)p3.x * 64 + lane]);
        float2 u4 = __half22float2(T2[(size_t)p4.x * 64 + lane]);
        float2 u5 = __half22float2(T2[(size_t)p5.x * 64 + lane]);
        float2 u6 = __half22float2(T2[(size_t)p6.x * 64 + lane]);
        float2 u7 = __half22float2(T2[(size_t)p7.x * 64 + lane]);
        float w0 = __int_as_float(p0.y), w1 = __int_as_float(p1.y);
        float w2 = __int_as_float(p2.y), w3 = __int_as_float(p3.y);
        float w4 = __int_as_float(p4.y), w5 = __int_as_float(p5.y);
        float w6 = __int_as_float(p6.y), w7 = __int_as_float(p7.y);
        acc.x += w0 * u0.x; acc.y += w0 * u0.y;
        acc.x += w1 * u1.x; acc.y += w1 * u1.y;
        acc.x += w2 * u2.x; acc.y += w2 * u2.y;
        acc.x += w3 * u3.x; acc.y += w3 * u3.y;
        acc.x += w4 * u4.x; acc.y += w4 * u4.y;
        acc.x += w5 * u5.x; acc.y += w5 * u5.y;
        acc.x += w6 * u6.x; acc.y += w6 * u6.y;
        acc.x += w7 * u7.x; acc.y += w7 * u7.y;
    }
    for (; e + 4 <= e1; e += 4) {
        int2 p0 = ew[e + 0], p1 = ew[e + 1], p2 = ew[e + 2], p3 = ew[e + 3];
        float2 u0 = __half22float2(T2[(size_t)p0.x * 64 + lane]);
        float2 u1 = __half22float2(T2[(size_t)p1.x * 64 + lane]);
        float2 u2 = __half22float2(T2[(size_t)p2.x * 64 + lane]);
        float2 u3 = __half22float2(T2[(size_t)p3.x * 64 + lane]);
        float w0 = __int_as_float(p0.y), w1 = __int_as_float(p1.y);
        float w2 = __int_as_float(p2.y), w3 = __int_as_float(p3.y);
        acc.x += w0 * u0.x; acc.y += w0 * u0.y;
        acc.x += w1 * u1.x; acc.y += w1 * u1.y;
        acc.x += w2 * u2.x; acc.y += w2 * u2.y;
        acc.x += w3 * u3.x; acc.y += w3 * u3.y;
    }
    for (; e < e1; ++e) {
        int2 p = ew[e];
        float w = __int_as_float(p.y);
        float2 u = __half22float2(T2[(size_t)p.x * 64 + lane]);
        acc.x += w * u.x;
        acc.y += w * u.y;
    }

    float2 b = ((const float2*)bias)[lane];
    __half2 o = __floats2half2_rn(fmaxf(acc.x + b.x, 0.f), fmaxf(acc.y + b.y, 0.f));
    ((__half2*)O)[(size_t)v * 64 + lane] = o;
}

// ---------------------------------------------------------------------------
// Global mean pool (fp16 in, fp32 out), split-parallel: grid (n_graphs, POOL_SPLIT)
// ---------------------------------------------------------------------------
__global__ __launch_bounds__(64) void pool_k(const __half* __restrict__ H,
                                             const int* __restrict__ batch,
                                             float* __restrict__ G, int n) {
    int g = blockIdx.x;
    int part = blockIdx.y;

    int lo = 0, hi = n;
    while (lo < hi) { int m = (lo + hi) >> 1; if (batch[m] < g) lo = m + 1; else hi = m; }
    int start = lo;
    lo = start; hi = n;
    while (lo < hi) { int m = (lo + hi) >> 1; if (batch[m] < g + 1) lo = m + 1; else hi = m; }
    int end = lo;
    int cnt = end - start;
    if (cnt <= 0) return;
    float inv = 1.0f / (float)cnt;

    int lane = threadIdx.x;
    const __half2* H2 = (const __half2*)H;
    float2 s = make_float2(0.f, 0.f);
    for (int v = start + part; v < end; v += POOL_SPLIT) {
        float2 h = __half22float2(H2[(size_t)v * 64 + lane]);
        s.x += h.x; s.y += h.y;
    }
    atomicAdd(&G[g * DIM + 2 * lane + 0], s.x * inv);
    atomicAdd(&G[g * DIM + 2 * lane + 1], s.y * inv);
}

// ---------------------------------------------------------------------------
// Head: y = relu(g@lin1+b1); logits = y@lin2+b2; out = log_softmax(logits)
// ---------------------------------------------------------------------------
__global__ __launch_bounds__(128) void head_k(const float* __restrict__ G,
                                              const float* __restrict__ l1w,
                                              const float* __restrict__ l1b,
                                              const float* __restrict__ l2w,
                                              const float* __restrict__ l2b,
                                              float* __restrict__ out) {
    int g = blockIdx.x;
    int j = threadIdx.x;
    __shared__ float gs[128];
    __shared__ float2 red[128];

    gs[j] = G[g * 128 + j];
    __syncthreads();

    float acc = l1b[j];
    for (int k = 0; k < 128; ++k) acc += gs[k] * l1w[k * 128 + j];
    float y = fmaxf(acc, 0.f);

    red[j] = make_float2(y * l2w[j * 2 + 0], y * l2w[j * 2 + 1]);
    __syncthreads();
    for (int s = 64; s > 0; s >>= 1) {
        if (j < s) {
            red[j].x += red[j + s].x;
            red[j].y += red[j + s].y;
        }
        __syncthreads();
    }
    if (j == 0) {
        float l0 = red[0].x + l2b[0];
        float l1 = red[0].y + l2b[1];
        float m = fmaxf(l0, l1);
        float lse = m + logf(expf(l0 - m) + expf(l1 - m));
        out[g * 2 + 0] = l0 - lse;
        out[g * 2 + 1] = l1 - lse;
    }
}

// ---------------------------------------------------------------------------
// Launch
// ---------------------------------------------------------------------------
extern "C" void kernel_launch(void* const* d_in, const int* in_sizes, int n_in,
                              void* d_out, int out_size, void* d_ws, size_t ws_size,
                              hipStream_t stream) {
    const float* x       = (const float*)d_in[0];
    const int*   ei      = (const int*)d_in[1];
    const int*   batch   = (const int*)d_in[2];
    const float* conv_w  = (const float*)d_in[3];
    const float* conv_b  = (const float*)d_in[4];
    const float* lin1_w  = (const float*)d_in[5];
    const float* lin1_b  = (const float*)d_in[6];
    const float* lin2_w  = (const float*)d_in[7];
    const float* lin2_b  = (const float*)d_in[8];
    float* out = (float*)d_out;

    const int n = in_sizes[0] / DIM;      // 100000
    const int E = in_sizes[1] / 2;        // 1600000
    const int n_graphs = 128;
    const int NBIN = (n + (1 << BINSH) - 1) >> BINSH;   // 98 dst-bins

    const int* src = ei;
    const int* dst = ei + E;

    // workspace layout (all 256B aligned)
    char* p = (char*)d_ws;
    auto alloc = [&](size_t bytes) {
        char* r = p;
        p += (bytes + 255) & ~(size_t)255;
        return r;
    };
    __half*    bufH    = (__half*)alloc((size_t)n * DIM * 2);  // agg output (fp16)
    __half*    bufT    = (__half*)alloc((size_t)n * DIM * 2);  // gemm output (fp16)
    float*     dis     = (float*)alloc((size_t)n * 4);
    int*       rowptr  = (int*)alloc((size_t)(n + 1) * 4);
    int*       binsize = (int*)alloc(128 * 4);
    int*       binbase = (int*)alloc(132 * 4);
    int*       bincur  = (int*)alloc((size_t)NBIN * 16 * 4);   // line-padded cursors
    int2*      tmp     = (int2*)alloc((size_t)E * 8);          // binned {src,dst}
    int2*      ew      = (int2*)alloc((size_t)E * 8);          // CSR {col, wgt}
    float*     gbuf    = (float*)alloc((size_t)n_graphs * DIM * 4);
    _Float16*  bp      = (_Float16*)alloc((size_t)3 * 2048 * 8 * 2);  // packed W frags
    (void)ws_size;

    const int binBlocks = (E + EPB - 1) / EPB;      // 98

    hipMemsetAsync(binsize, 0, 128 * 4, stream);
    hipMemsetAsync(gbuf, 0, (size_t)n_graphs * DIM * 4, stream);
    wpack_k<<<24, 256, 0, stream>>>(conv_w, bp);
    bincount_k<<<binBlocks, 256, 0, stream>>>(dst, binsize, E, NBIN);
    binscan2_k<<<1, 128, 0, stream>>>(binsize, binbase, bincur, NBIN, E);
    bin_k<<<binBlocks, 256, 0, stream>>>(src, dst, bincur, tmp, E, NBIN);
    rowcnt_k<<<NBIN, 256, 0, stream>>>(tmp, binbase, rowptr, dis, n, E, NBIN);
    fill2_k<<<NBIN, 256, 0, stream>>>(tmp, rowptr, dis, ew, n);

    const int gemmBlocks = (n + 63) / 64;
    const int aggBlocks = (n + 3) / 4;

    // layer 0: x (fp32) -> bufT -> bufH
    gemm_k<false><<<gemmBlocks, 256, 0, stream>>>((const void*)x, bp + 0 * 16384, bufT, n);
    agg_k<<<aggBlocks, 256, 0, stream>>>(bufT, rowptr, ew, dis, conv_b + 0 * DIM, bufH, n);
    // layer 1
    gemm_k<true><<<gemmBlocks, 256, 0, stream>>>((const void*)bufH, bp + 1 * 16384, bufT, n);
    agg_k<<<aggBlocks, 256, 0, stream>>>(bufT, rowptr, ew, dis, conv_b + 1 * DIM, bufH, n);
    // layer 2
    gemm_k<true><<<gemmBlocks, 256, 0, stream>>>((const void*)bufH, bp + 2 * 16384, bufT, n);
    agg_k<<<aggBlocks, 256, 0, stream>>>(bufT, rowptr, ew, dis, conv_b + 2 * DIM, bufH, n);

    dim3 pgrid(n_graphs, POOL_SPLIT);
    pool_k<<<pgrid, 64, 0, stream>>>(bufH, batch, gbuf, n);
    head_k<<<n_graphs, 128, 0, stream>>>(gbuf, lin1_w, lin1_b, lin2_w, lin2_b, out);
}

// Round 11
// 469.689 us; speedup vs baseline: 1.8258x; 1.0491x over previous
//
#include <hip/hip_runtime.h>
#include <hip/hip_fp16.h>
#include <math.h>

#define DIM 128
#define POOL_SPLIT 32  // partial-sum blocks per graph
#define BINSH 10       // 1024 nodes per dst-bin
#define EPB 16384      // edges per bin_k block
#define ALH 136        // gemm A-tile LDS row stride in halves
// Build discipline (R6): per-EDGE global atomics ping-pong cache lines across
// the 8 non-coherent XCD L2s — catastrophic. All per-edge counting in LDS.
// Agg discipline (R9): 8/4 unroll + VGPR<=32 is the measured optimum; wider
// unroll trades occupancy for MLP at a net loss.
// Agg is fetch-bound: dur == FETCH / ~3.2 TB/s (R7-R10 identity). This round:
// T stored as fp8 e4m3 (OCP, gfx950 HW cvt) -> 128B/row gather, FETCH halves.
// fp32 accumulate everywhere; bufH (gemm input) stays fp16.

typedef __attribute__((ext_vector_type(8))) _Float16 half8;
typedef __attribute__((ext_vector_type(4))) float f32x4;
typedef __attribute__((ext_vector_type(2))) float f32x2;

// ---------------------------------------------------------------------------
// Graph build: bincount -> binscan -> bin -> rowcnt -> fill2
// ---------------------------------------------------------------------------

__global__ __launch_bounds__(256) void bincount_k(const int* __restrict__ dst,
                                                  int* __restrict__ binsize,
                                                  int E, int NBIN) {
    __shared__ int h[128];
    const int t = threadIdx.x;
    if (t < 128) h[t] = 0;
    __syncthreads();
    const int e0 = blockIdx.x * EPB;
    const int e1 = min(e0 + EPB, E);
    for (int e = e0 + t; e < e1; e += 256)
        atomicAdd(&h[dst[e] >> BINSH], 1);
    __syncthreads();
    if (t < NBIN && h[t]) atomicAdd(&binsize[t], h[t]);
}

__global__ void binscan2_k(const int* __restrict__ binsize, int* __restrict__ binbase,
                           int* __restrict__ bincur, int NBIN, int E) {
    __shared__ int s[128];
    const int t = threadIdx.x;   // 128 threads
    int v = (t < NBIN) ? binsize[t] : 0;
    s[t] = v;
    __syncthreads();
    for (int off = 1; off < 128; off <<= 1) {
        int u = (t >= off) ? s[t - off] : 0;
        __syncthreads();
        s[t] += u;
        __syncthreads();
    }
    int excl = s[t] - v;
    if (t < NBIN) { binbase[t] = excl; bincur[t * 16] = excl; }
    if (t == 0) binbase[NBIN] = E;
}

__global__ __launch_bounds__(256) void bin_k(const int* __restrict__ src,
                                             const int* __restrict__ dst,
                                             int* __restrict__ bincur,
                                             int2* __restrict__ tmp, int E, int NBIN) {
    __shared__ int cur[128];
    const int t = threadIdx.x;
    if (t < 128) cur[t] = 0;
    __syncthreads();
    const int e0 = blockIdx.x * EPB;
    const int e1 = min(e0 + EPB, E);
    for (int e = e0 + t; e < e1; e += 256)
        atomicAdd(&cur[dst[e] >> BINSH], 1);
    __syncthreads();
    if (t < NBIN) {
        int h = cur[t];
        cur[t] = h ? atomicAdd(&bincur[t * 16], h) : 0;
    }
    __syncthreads();
    for (int e = e0 + t; e < e1; e += 256) {
        int d = dst[e], s = src[e];
        int pos = atomicAdd(&cur[d >> BINSH], 1);
        tmp[pos] = make_int2(s, d);
    }
}

__global__ __launch_bounds__(256) void rowcnt_k(const int2* __restrict__ tmp,
                                                const int* __restrict__ binbase,
                                                int* __restrict__ rowptr,
                                                float* __restrict__ dis,
                                                int n, int E, int NBIN) {
    __shared__ int cnt[1 << BINSH];
    __shared__ int part[256];
    const int b = blockIdx.x, t = threadIdx.x;
    for (int i = t; i < (1 << BINSH); i += 256) cnt[i] = 0;
    __syncthreads();
    const int ebeg = binbase[b], eend = binbase[b + 1];
    for (int e = ebeg + t; e < eend; e += 256)
        atomicAdd(&cnt[tmp[e].y & ((1 << BINSH) - 1)], 1);
    __syncthreads();
    int cc[4];
    cc[0] = cnt[t * 4 + 0]; cc[1] = cnt[t * 4 + 1];
    cc[2] = cnt[t * 4 + 2]; cc[3] = cnt[t * 4 + 3];
    int s = cc[0] + cc[1] + cc[2] + cc[3];
    part[t] = s;
    __syncthreads();
    for (int off = 1; off < 256; off <<= 1) {
        int u = (t >= off) ? part[t - off] : 0;
        __syncthreads();
        part[t] += u;
        __syncthreads();
    }
    int off0 = ebeg + part[t] - s;
    int node0 = (b << BINSH) + t * 4;
    int pre = 0;
#pragma unroll
    for (int j = 0; j < 4; ++j) {
        int node = node0 + j;
        if (node < n) {
            rowptr[node] = off0 + pre;
            dis[node] = rsqrtf((float)(cc[j] + 1));
        }
        pre += cc[j];
    }
    if (b == NBIN - 1 && t == 0) rowptr[n] = E;
}

__global__ __launch_bounds__(256) void fill2_k(const int2* __restrict__ tmp,
                                               const int* __restrict__ rowptr,
                                               const float* __restrict__ dis,
                                               int2* __restrict__ ew, int n) {
    __shared__ int lcur[1 << BINSH];
    const int base_node = blockIdx.x << BINSH;
    const int t = threadIdx.x;
    for (int i = t; i < (1 << BINSH); i += 256)
        if (base_node + i < n) lcur[i] = rowptr[base_node + i];
    const int e_begin = rowptr[base_node];
    const int e_end   = rowptr[min(base_node + (1 << BINSH), n)];
    __syncthreads();
    for (int e = e_begin + t; e < e_end; e += 256) {
        int2 r = tmp[e];
        float w = dis[r.x] * dis[r.y];
        int q = atomicAdd(&lcur[r.y & ((1 << BINSH) - 1)], 1);
        ew[q] = make_int2(r.x, __float_as_int(w));
    }
}

// ---------------------------------------------------------------------------
// Weight pre-pack: conv_w (fp32 [k][col]) -> fp16 MFMA A-operand fragment
// order. For 16x16x32: lane (quad=l>>4, m=l&15) holds elem [m][quad*8+j].
// ---------------------------------------------------------------------------
__global__ void wpack_k(const float* __restrict__ conv_w, _Float16* __restrict__ bp) {
    int g = blockIdx.x * 256 + threadIdx.x;   // 3 * 2048
    if (g >= 3 * 2048) return;
    int l = g >> 11;
    int rem = g & 2047;
    int c = rem >> 8;
    int f = (rem >> 6) & 3;
    int lane = rem & 63;
    const float* W = conv_w + l * DIM * DIM;
    int kbase = f * 32 + (lane >> 4) * 8;
    int col = c * 16 + (lane & 15);
    _Float16* d = bp + ((size_t)l * 2048 + (size_t)(c * 4 + f) * 64 + lane) * 8;
#pragma unroll
    for (int j = 0; j < 8; ++j)
        d[j] = (_Float16)W[(kbase + j) * DIM + col];
}

// ---------------------------------------------------------------------------
// MFMA GEMM: T[n,128](fp8 e4m3) = A[n,128] @ W ; fp32 accumulate. D^T via
// operand swap mfma(b,a,acc) -> lane owns 4 consecutive cols of one row ->
// one packed 4B fp8 store per c-tile (v_cvt_pk_fp8_f32 x2).
// ---------------------------------------------------------------------------
template <bool FP16IN>
__global__ __launch_bounds__(256) void gemm_k(const void* __restrict__ Ain,
                                              const _Float16* __restrict__ Bp,
                                              unsigned int* __restrict__ T32, int n) {
    __shared__ _Float16 Al[64 * ALH];
    const int t = threadIdx.x;
    const int r0 = blockIdx.x * 64;
    const int nrows = min(64, n - r0);

    if (FP16IN) {
        const _Float16* A = (const _Float16*)Ain;
        for (int idx = t; idx < 64 * 16; idx += 256) {
            int row = idx >> 4, c = idx & 15;
            half8 v = {};
            if (row < nrows) v = *(const half8*)(A + (size_t)(r0 + row) * DIM + c * 8);
            *(half8*)&Al[row * ALH + c * 8] = v;
        }
    } else {
        const float* A = (const float*)Ain;
        for (int idx = t; idx < 64 * 32; idx += 256) {
            int row = idx >> 5, c = idx & 31;
            float4 v = make_float4(0.f, 0.f, 0.f, 0.f);
            if (row < nrows) v = ((const float4*)(A + (size_t)(r0 + row) * DIM))[c];
            __half2 h01 = __floats2half2_rn(v.x, v.y);
            __half2 h23 = __floats2half2_rn(v.z, v.w);
            *(int2*)&Al[row * ALH + c * 4] = make_int2(*(int*)&h01, *(int*)&h23);
        }
    }
    __syncthreads();

    const int lane = t & 63;
    const int wave = t >> 6;
    const int quad = lane >> 4;
    const int m    = lane & 15;
    const int lrow = wave * 16 + m;
    const int row  = r0 + lrow;

    half8 a[4];
#pragma unroll
    for (int f = 0; f < 4; ++f)
        a[f] = *(const half8*)&Al[lrow * ALH + f * 32 + quad * 8];

    const half8* B8 = (const half8*)Bp;   // 32KB/layer, hot in L1
#pragma unroll
    for (int c = 0; c < 8; ++c) {
        f32x4 acc = {0.f, 0.f, 0.f, 0.f};
#pragma unroll
        for (int f = 0; f < 4; ++f) {
            half8 b = B8[(c * 4 + f) * 64 + lane];
            acc = __builtin_amdgcn_mfma_f32_16x16x32_f16(b, a[f], acc, 0, 0, 0);
        }
        if (row < n) {
            int r = 0;
            r = __builtin_amdgcn_cvt_pk_fp8_f32(acc[0], acc[1], r, 0);
            r = __builtin_amdgcn_cvt_pk_fp8_f32(acc[2], acc[3], r, 1);
            T32[(size_t)row * 32 + c * 4 + quad] = (unsigned int)r;
        }
    }
}

// ---------------------------------------------------------------------------
// Aggregation: O[v] = relu( dis[v]^2 * T[v] + sum_e wgt[e]*T[col[e]] + b )
// one wave per node; fp8 gather (1 ushort = 2 dims per lane, 128B/row),
// fp32 accumulate, fp16 out. 8/4 unroll (R8 measured optimum).
// ---------------------------------------------------------------------------
__global__ __launch_bounds__(256) void agg_k(const unsigned short* __restrict__ T8,
                                             const int* __restrict__ rowptr,
                                             const int2* __restrict__ ew,
                                             const float* __restrict__ dis,
                                             const float* __restrict__ bias,
                                             __half* __restrict__ O, int n) {
    int lane = threadIdx.x & 63;
    int v = blockIdx.x * 4 + (threadIdx.x >> 6);
    if (v >= n) return;

    float dv = dis[v];
    int e0 = rowptr[v], e1 = rowptr[v + 1];

    f32x2 t = __builtin_amdgcn_cvt_pk_f32_fp8((int)T8[(size_t)v * 64 + lane], 0);
    float2 acc;
    acc.x = t[0] * dv * dv;
    acc.y = t[1] * dv * dv;

    int e = e0;
    for (; e + 8 <= e1; e += 8) {
        int2 p0 = ew[e + 0], p1 = ew[e + 1], p2 = ew[e + 2], p3 = ew[e + 3];
        int2 p4 = ew[e + 4], p5 = ew[e + 5], p6 = ew[e + 6], p7 = ew[e + 7];
        int r0 = T8[(size_t)p0.x * 64 + lane];
        int r1 = T8[(size_t)p1.x * 64 + lane];
        int r2 = T8[(size_t)p2.x * 64 + lane];
        int r3 = T8[(size_t)p3.x * 64 + lane];
        int r4 = T8[(size_t)p4.x * 64 + lane];
        int r5 = T8[(size_t)p5.x * 64 + lane];
        int r6 = T8[(size_t)p6.x * 64 + lane];
        int r7 = T8[(size_t)p7.x * 64 + lane];
        f32x2 u0 = __builtin_amdgcn_cvt_pk_f32_fp8(r0, 0);
        f32x2 u1 = __builtin_amdgcn_cvt_pk_f32_fp8(r1, 0);
        f32x2 u2 = __builtin_amdgcn_cvt_pk_f32_fp8(r2, 0);
        f32x2 u3 = __builtin_amdgcn_cvt_pk_f32_fp8(r3, 0);
        f32x2 u4 = __builtin_amdgcn_cvt_pk_f32_fp8(r4, 0);
        f32x2 u5 = __builtin_amdgcn_cvt_pk_f32_fp8(r5, 0);
        f32x2 u6 = __builtin_amdgcn_cvt_pk_f32_fp8(r6, 0);
        f32x2 u7 = __builtin_amdgcn_cvt_pk_f32_fp8(r7, 0);
        float w0 = __int_as_float(p0.y), w1 = __int_as_float(p1.y);
        float w2 = __int_as_float(p2.y), w3 = __int_as_float(p3.y);
        float w4 = __int_as_float(p4.y), w5 = __int_as_float(p5.y);
        float w6 = __int_as_float(p6.y), w7 = __int_as_float(p7.y);
        acc.x += w0 * u0[0]; acc.y += w0 * u0[1];
        acc.x += w1 * u1[0]; acc.y += w1 * u1[1];
        acc.x += w2 * u2[0]; acc.y += w2 * u2[1];
        acc.x += w3 * u3[0]; acc.y += w3 * u3[1];
        acc.x += w4 * u4[0]; acc.y += w4 * u4[1];
        acc.x += w5 * u5[0]; acc.y += w5 * u5[1];
        acc.x += w6 * u6[0]; acc.y += w6 * u6[1];
        acc.x += w7 * u7[0]; acc.y += w7 * u7[1];
    }
    for (; e + 4 <= e1; e += 4) {
        int2 p0 = ew[e + 0], p1 = ew[e + 1], p2 = ew[e + 2], p3 = ew[e + 3];
        int r0 = T8[(size_t)p0.x * 64 + lane];
        int r1 = T8[(size_t)p1.x * 64 + lane];
        int r2 = T8[(size_t)p2.x * 64 + lane];
        int r3 = T8[(size_t)p3.x * 64 + lane];
        f32x2 u0 = __builtin_amdgcn_cvt_pk_f32_fp8(r0, 0);
        f32x2 u1 = __builtin_amdgcn_cvt_pk_f32_fp8(r1, 0);
        f32x2 u2 = __builtin_amdgcn_cvt_pk_f32_fp8(r2, 0);
        f32x2 u3 = __builtin_amdgcn_cvt_pk_f32_fp8(r3, 0);
        float w0 = __int_as_float(p0.y), w1 = __int_as_float(p1.y);
        float w2 = __int_as_float(p2.y), w3 = __int_as_float(p3.y);
        acc.x += w0 * u0[0]; acc.y += w0 * u0[1];
        acc.x += w1 * u1[0]; acc.y += w1 * u1[1];
        acc.x += w2 * u2[0]; acc.y += w2 * u2[1];
        acc.x += w3 * u3[0]; acc.y += w3 * u3[1];
    }
    for (; e < e1; ++e) {
        int2 p = ew[e];
        float w = __int_as_float(p.y);
        f32x2 u = __builtin_amdgcn_cvt_pk_f32_fp8((int)T8[(size_t)p.x * 64 + lane], 0);
        acc.x += w * u[0];
        acc.y += w * u[1];
    }

    float2 b = ((const float2*)bias)[lane];
    __half2 o = __floats2half2_rn(fmaxf(acc.x + b.x, 0.f), fmaxf(acc.y + b.y, 0.f));
    ((__half2*)O)[(size_t)v * 64 + lane] = o;
}

// ---------------------------------------------------------------------------
// Global mean pool (fp16 in, fp32 out), split-parallel: grid (n_graphs, POOL_SPLIT)
// ---------------------------------------------------------------------------
__global__ __launch_bounds__(64) void pool_k(const __half* __restrict__ H,
                                             const int* __restrict__ batch,
                                             float* __restrict__ G, int n) {
    int g = blockIdx.x;
    int part = blockIdx.y;

    int lo = 0, hi = n;
    while (lo < hi) { int m = (lo + hi) >> 1; if (batch[m] < g) lo = m + 1; else hi = m; }
    int start = lo;
    lo = start; hi = n;
    while (lo < hi) { int m = (lo + hi) >> 1; if (batch[m] < g + 1) lo = m + 1; else hi = m; }
    int end = lo;
    int cnt = end - start;
    if (cnt <= 0) return;
    float inv = 1.0f / (float)cnt;

    int lane = threadIdx.x;
    const __half2* H2 = (const __half2*)H;
    float2 s = make_float2(0.f, 0.f);
    for (int v = start + part; v < end; v += POOL_SPLIT) {
        float2 h = __half22float2(H2[(size_t)v * 64 + lane]);
        s.x += h.x; s.y += h.y;
    }
    atomicAdd(&G[g * DIM + 2 * lane + 0], s.x * inv);
    atomicAdd(&G[g * DIM + 2 * lane + 1], s.y * inv);
}

// ---------------------------------------------------------------------------
// Head: y = relu(g@lin1+b1); logits = y@lin2+b2; out = log_softmax(logits)
// ---------------------------------------------------------------------------
__global__ __launch_bounds__(128) void head_k(const float* __restrict__ G,
                                              const float* __restrict__ l1w,
                                              const float* __restrict__ l1b,
                                              const float* __restrict__ l2w,
                                              const float* __restrict__ l2b,
                                              float* __restrict__ out) {
    int g = blockIdx.x;
    int j = threadIdx.x;
    __shared__ float gs[128];
    __shared__ float2 red[128];

    gs[j] = G[g * 128 + j];
    __syncthreads();

    float acc = l1b[j];
    for (int k = 0; k < 128; ++k) acc += gs[k] * l1w[k * 128 + j];
    float y = fmaxf(acc, 0.f);

    red[j] = make_float2(y * l2w[j * 2 + 0], y * l2w[j * 2 + 1]);
    __syncthreads();
    for (int s = 64; s > 0; s >>= 1) {
        if (j < s) {
            red[j].x += red[j + s].x;
            red[j].y += red[j + s].y;
        }
        __syncthreads();
    }
    if (j == 0) {
        float l0 = red[0].x + l2b[0];
        float l1 = red[0].y + l2b[1];
        float m = fmaxf(l0, l1);
        float lse = m + logf(expf(l0 - m) + expf(l1 - m));
        out[g * 2 + 0] = l0 - lse;
        out[g * 2 + 1] = l1 - lse;
    }
}

// ---------------------------------------------------------------------------
// Launch
// ---------------------------------------------------------------------------
extern "C" void kernel_launch(void* const* d_in, const int* in_sizes, int n_in,
                              void* d_out, int out_size, void* d_ws, size_t ws_size,
                              hipStream_t stream) {
    const float* x       = (const float*)d_in[0];
    const int*   ei      = (const int*)d_in[1];
    const int*   batch   = (const int*)d_in[2];
    const float* conv_w  = (const float*)d_in[3];
    const float* conv_b  = (const float*)d_in[4];
    const float* lin1_w  = (const float*)d_in[5];
    const float* lin1_b  = (const float*)d_in[6];
    const float* lin2_w  = (const float*)d_in[7];
    const float* lin2_b  = (const float*)d_in[8];
    float* out = (float*)d_out;

    const int n = in_sizes[0] / DIM;      // 100000
    const int E = in_sizes[1] / 2;        // 1600000
    const int n_graphs = 128;
    const int NBIN = (n + (1 << BINSH) - 1) >> BINSH;   // 98 dst-bins

    const int* src = ei;
    const int* dst = ei + E;

    // workspace layout (all 256B aligned)
    char* p = (char*)d_ws;
    auto alloc = [&](size_t bytes) {
        char* r = p;
        p += (bytes + 255) & ~(size_t)255;
        return r;
    };
    __half*        bufH    = (__half*)alloc((size_t)n * DIM * 2);       // agg output (fp16)
    unsigned int*  bufT    = (unsigned int*)alloc((size_t)n * DIM);     // gemm output (fp8)
    float*         dis     = (float*)alloc((size_t)n * 4);
    int*           rowptr  = (int*)alloc((size_t)(n + 1) * 4);
    int*           binsize = (int*)alloc(128 * 4);
    int*           binbase = (int*)alloc(132 * 4);
    int*           bincur  = (int*)alloc((size_t)NBIN * 16 * 4);
    int2*          tmp     = (int2*)alloc((size_t)E * 8);               // binned {src,dst}
    int2*          ew      = (int2*)alloc((size_t)E * 8);               // CSR {col, wgt}
    float*         gbuf    = (float*)alloc((size_t)n_graphs * DIM * 4);
    _Float16*      bp      = (_Float16*)alloc((size_t)3 * 2048 * 8 * 2);
    (void)ws_size;

    const int binBlocks = (E + EPB - 1) / EPB;      // 98

    hipMemsetAsync(binsize, 0, 128 * 4, stream);
    hipMemsetAsync(gbuf, 0, (size_t)n_graphs * DIM * 4, stream);
    wpack_k<<<24, 256, 0, stream>>>(conv_w, bp);
    bincount_k<<<binBlocks, 256, 0, stream>>>(dst, binsize, E, NBIN);
    binscan2_k<<<1, 128, 0, stream>>>(binsize, binbase, bincur, NBIN, E);
    bin_k<<<binBlocks, 256, 0, stream>>>(src, dst, bincur, tmp, E, NBIN);
    rowcnt_k<<<NBIN, 256, 0, stream>>>(tmp, binbase, rowptr, dis, n, E, NBIN);
    fill2_k<<<NBIN, 256, 0, stream>>>(tmp, rowptr, dis, ew, n);

    const int gemmBlocks = (n + 63) / 64;
    const int aggBlocks = (n + 3) / 4;

    // layer 0: x (fp32) -> bufT(fp8) -> bufH(fp16)
    gemm_k<false><<<gemmBlocks, 256, 0, stream>>>((const void*)x, bp + 0 * 16384, bufT, n);
    agg_k<<<aggBlocks, 256, 0, stream>>>((const unsigned short*)bufT, rowptr, ew, dis, conv_b + 0 * DIM, bufH, n);
    // layer 1
    gemm_k<true><<<gemmBlocks, 256, 0, stream>>>((const void*)bufH, bp + 1 * 16384, bufT, n);
    agg_k<<<aggBlocks, 256, 0, stream>>>((const unsigned short*)bufT, rowptr, ew, dis, conv_b + 1 * DIM, bufH, n);
    // layer 2
    gemm_k<true><<<gemmBlocks, 256, 0, stream>>>((const void*)bufH, bp + 2 * 16384, bufT, n);
    agg_k<<<aggBlocks, 256, 0, stream>>>((const unsigned short*)bufT, rowptr, ew, dis, conv_b + 2 * DIM, bufH, n);

    dim3 pgrid(n_graphs, POOL_SPLIT);
    pool_k<<<pgrid, 64, 0, stream>>>(bufH, batch, gbuf, n);
    head_k<<<n_graphs, 128, 0, stream>>>(gbuf, lin1_w, lin1_b, lin2_w, lin2_b, out);
}

// Round 12
// 459.490 us; speedup vs baseline: 1.8663x; 1.0222x over previous
//
#include <hip/hip_runtime.h>
#include <hip/hip_fp16.h>
#include <math.h>

#define DIM 128
#define POOL_SPLIT 32  // partial-sum blocks per graph
#define BINSH 10       // 1024 nodes per dst-bin
#define EPB 16384      // edges per bin_k block
#define ALH 136        // gemm A-tile LDS row stride in halves
// Build discipline (R6): per-EDGE global atomics ping-pong cache lines across
// the 8 non-coherent XCD L2s — catastrophic. All per-edge counting in LDS.
// Agg discipline (R9/R11): 8/4 unroll optimum; after fp8 (R11) agg became
// gather-ISSUE-bound (FETCH halved, dur -11% only). This round: 4 fp8 dims
// per lane -> 32 lanes/row -> one wave-gather serves TWO edges; halves the
// gather instruction count. Cross-half merge via one shfl_xor(32) at the end.

typedef __attribute__((ext_vector_type(8))) _Float16 half8;
typedef __attribute__((ext_vector_type(4))) float f32x4;
typedef __attribute__((ext_vector_type(2))) float f32x2;

// ---------------------------------------------------------------------------
// Graph build: bincount -> binscan -> bin -> rowcnt -> fill2
// ---------------------------------------------------------------------------

__global__ __launch_bounds__(256) void bincount_k(const int* __restrict__ dst,
                                                  int* __restrict__ binsize,
                                                  int E, int NBIN) {
    __shared__ int h[128];
    const int t = threadIdx.x;
    if (t < 128) h[t] = 0;
    __syncthreads();
    const int e0 = blockIdx.x * EPB;
    const int e1 = min(e0 + EPB, E);
    for (int e = e0 + t; e < e1; e += 256)
        atomicAdd(&h[dst[e] >> BINSH], 1);
    __syncthreads();
    if (t < NBIN && h[t]) atomicAdd(&binsize[t], h[t]);
}

__global__ void binscan2_k(const int* __restrict__ binsize, int* __restrict__ binbase,
                           int* __restrict__ bincur, int NBIN, int E) {
    __shared__ int s[128];
    const int t = threadIdx.x;   // 128 threads
    int v = (t < NBIN) ? binsize[t] : 0;
    s[t] = v;
    __syncthreads();
    for (int off = 1; off < 128; off <<= 1) {
        int u = (t >= off) ? s[t - off] : 0;
        __syncthreads();
        s[t] += u;
        __syncthreads();
    }
    int excl = s[t] - v;
    if (t < NBIN) { binbase[t] = excl; bincur[t * 16] = excl; }
    if (t == 0) binbase[NBIN] = E;
}

__global__ __launch_bounds__(256) void bin_k(const int* __restrict__ src,
                                             const int* __restrict__ dst,
                                             int* __restrict__ bincur,
                                             int2* __restrict__ tmp, int E, int NBIN) {
    __shared__ int cur[128];
    const int t = threadIdx.x;
    if (t < 128) cur[t] = 0;
    __syncthreads();
    const int e0 = blockIdx.x * EPB;
    const int e1 = min(e0 + EPB, E);
    for (int e = e0 + t; e < e1; e += 256)
        atomicAdd(&cur[dst[e] >> BINSH], 1);
    __syncthreads();
    if (t < NBIN) {
        int h = cur[t];
        cur[t] = h ? atomicAdd(&bincur[t * 16], h) : 0;
    }
    __syncthreads();
    for (int e = e0 + t; e < e1; e += 256) {
        int d = dst[e], s = src[e];
        int pos = atomicAdd(&cur[d >> BINSH], 1);
        tmp[pos] = make_int2(s, d);
    }
}

__global__ __launch_bounds__(256) void rowcnt_k(const int2* __restrict__ tmp,
                                                const int* __restrict__ binbase,
                                                int* __restrict__ rowptr,
                                                float* __restrict__ dis,
                                                int n, int E, int NBIN) {
    __shared__ int cnt[1 << BINSH];
    __shared__ int part[256];
    const int b = blockIdx.x, t = threadIdx.x;
    for (int i = t; i < (1 << BINSH); i += 256) cnt[i] = 0;
    __syncthreads();
    const int ebeg = binbase[b], eend = binbase[b + 1];
    for (int e = ebeg + t; e < eend; e += 256)
        atomicAdd(&cnt[tmp[e].y & ((1 << BINSH) - 1)], 1);
    __syncthreads();
    int cc[4];
    cc[0] = cnt[t * 4 + 0]; cc[1] = cnt[t * 4 + 1];
    cc[2] = cnt[t * 4 + 2]; cc[3] = cnt[t * 4 + 3];
    int s = cc[0] + cc[1] + cc[2] + cc[3];
    part[t] = s;
    __syncthreads();
    for (int off = 1; off < 256; off <<= 1) {
        int u = (t >= off) ? part[t - off] : 0;
        __syncthreads();
        part[t] += u;
        __syncthreads();
    }
    int off0 = ebeg + part[t] - s;
    int node0 = (b << BINSH) + t * 4;
    int pre = 0;
#pragma unroll
    for (int j = 0; j < 4; ++j) {
        int node = node0 + j;
        if (node < n) {
            rowptr[node] = off0 + pre;
            dis[node] = rsqrtf((float)(cc[j] + 1));
        }
        pre += cc[j];
    }
    if (b == NBIN - 1 && t == 0) rowptr[n] = E;
}

__global__ __launch_bounds__(256) void fill2_k(const int2* __restrict__ tmp,
                                               const int* __restrict__ rowptr,
                                               const float* __restrict__ dis,
                                               int2* __restrict__ ew, int n) {
    __shared__ int lcur[1 << BINSH];
    const int base_node = blockIdx.x << BINSH;
    const int t = threadIdx.x;
    for (int i = t; i < (1 << BINSH); i += 256)
        if (base_node + i < n) lcur[i] = rowptr[base_node + i];
    const int e_begin = rowptr[base_node];
    const int e_end   = rowptr[min(base_node + (1 << BINSH), n)];
    __syncthreads();
    for (int e = e_begin + t; e < e_end; e += 256) {
        int2 r = tmp[e];
        float w = dis[r.x] * dis[r.y];
        int q = atomicAdd(&lcur[r.y & ((1 << BINSH) - 1)], 1);
        ew[q] = make_int2(r.x, __float_as_int(w));
    }
}

// ---------------------------------------------------------------------------
// Weight pre-pack: conv_w (fp32 [k][col]) -> fp16 MFMA A-operand fragment order
// ---------------------------------------------------------------------------
__global__ void wpack_k(const float* __restrict__ conv_w, _Float16* __restrict__ bp) {
    int g = blockIdx.x * 256 + threadIdx.x;   // 3 * 2048
    if (g >= 3 * 2048) return;
    int l = g >> 11;
    int rem = g & 2047;
    int c = rem >> 8;
    int f = (rem >> 6) & 3;
    int lane = rem & 63;
    const float* W = conv_w + l * DIM * DIM;
    int kbase = f * 32 + (lane >> 4) * 8;
    int col = c * 16 + (lane & 15);
    _Float16* d = bp + ((size_t)l * 2048 + (size_t)(c * 4 + f) * 64 + lane) * 8;
#pragma unroll
    for (int j = 0; j < 8; ++j)
        d[j] = (_Float16)W[(kbase + j) * DIM + col];
}

// ---------------------------------------------------------------------------
// MFMA GEMM: T[n,128](fp8 e4m3) = A[n,128] @ W ; fp32 accumulate. D^T via
// operand swap -> lane owns 4 consecutive cols -> one packed 4B fp8 store.
// Word w of row contains dims 4w..4w+3.
// ---------------------------------------------------------------------------
template <bool FP16IN>
__global__ __launch_bounds__(256) void gemm_k(const void* __restrict__ Ain,
                                              const _Float16* __restrict__ Bp,
                                              unsigned int* __restrict__ T32, int n) {
    __shared__ _Float16 Al[64 * ALH];
    const int t = threadIdx.x;
    const int r0 = blockIdx.x * 64;
    const int nrows = min(64, n - r0);

    if (FP16IN) {
        const _Float16* A = (const _Float16*)Ain;
        for (int idx = t; idx < 64 * 16; idx += 256) {
            int row = idx >> 4, c = idx & 15;
            half8 v = {};
            if (row < nrows) v = *(const half8*)(A + (size_t)(r0 + row) * DIM + c * 8);
            *(half8*)&Al[row * ALH + c * 8] = v;
        }
    } else {
        const float* A = (const float*)Ain;
        for (int idx = t; idx < 64 * 32; idx += 256) {
            int row = idx >> 5, c = idx & 31;
            float4 v = make_float4(0.f, 0.f, 0.f, 0.f);
            if (row < nrows) v = ((const float4*)(A + (size_t)(r0 + row) * DIM))[c];
            __half2 h01 = __floats2half2_rn(v.x, v.y);
            __half2 h23 = __floats2half2_rn(v.z, v.w);
            *(int2*)&Al[row * ALH + c * 4] = make_int2(*(int*)&h01, *(int*)&h23);
        }
    }
    __syncthreads();

    const int lane = t & 63;
    const int wave = t >> 6;
    const int quad = lane >> 4;
    const int m    = lane & 15;
    const int lrow = wave * 16 + m;
    const int row  = r0 + lrow;

    half8 a[4];
#pragma unroll
    for (int f = 0; f < 4; ++f)
        a[f] = *(const half8*)&Al[lrow * ALH + f * 32 + quad * 8];

    const half8* B8 = (const half8*)Bp;   // 32KB/layer, hot in L1
#pragma unroll
    for (int c = 0; c < 8; ++c) {
        f32x4 acc = {0.f, 0.f, 0.f, 0.f};
#pragma unroll
        for (int f = 0; f < 4; ++f) {
            half8 b = B8[(c * 4 + f) * 64 + lane];
            acc = __builtin_amdgcn_mfma_f32_16x16x32_f16(b, a[f], acc, 0, 0, 0);
        }
        if (row < n) {
            int r = 0;
            r = __builtin_amdgcn_cvt_pk_fp8_f32(acc[0], acc[1], r, 0);
            r = __builtin_amdgcn_cvt_pk_fp8_f32(acc[2], acc[3], r, 1);
            T32[(size_t)row * 32 + c * 4 + quad] = (unsigned int)r;
        }
    }
}

// ---------------------------------------------------------------------------
// Aggregation: O[v] = relu( dis[v]^2 * T[v] + sum_e wgt[e]*T[col[e]] + b )
// one wave per node; lane = (half h, word li): loads uint = 4 fp8 dims at
// word li of its half's edge row -> ONE wave-gather serves TWO edges.
// Cross-half merge: shfl_xor(32) x4 at the end; lanes 0-31 store 8B fp16.
// fp32 accumulate throughout.
// ---------------------------------------------------------------------------
__global__ __launch_bounds__(256) void agg_k(const unsigned int* __restrict__ T32,
                                             const int* __restrict__ rowptr,
                                             const int2* __restrict__ ew,
                                             const float* __restrict__ dis,
                                             const float* __restrict__ bias,
                                             __half* __restrict__ O, int n) {
    const int lane = threadIdx.x & 63;
    const int h    = lane >> 5;        // which edge of the pair
    const int li   = lane & 31;        // word (4 dims) within row
    const int v = blockIdx.x * 4 + (threadIdx.x >> 6);
    if (v >= n) return;

    float dv = dis[v];
    int e0 = rowptr[v], e1 = rowptr[v + 1];

    f32x4 acc = {0.f, 0.f, 0.f, 0.f};
    // self term (half 0 only; half 1's load is a broadcast of the same line)
    {
        unsigned int r = T32[(size_t)v * 32 + li];
        if (h == 0) {
            f32x2 lo = __builtin_amdgcn_cvt_pk_f32_fp8((int)r, 0);
            f32x2 hi = __builtin_amdgcn_cvt_pk_f32_fp8((int)r, 1);
            float w = dv * dv;
            acc[0] += w * lo[0]; acc[1] += w * lo[1];
            acc[2] += w * hi[0]; acc[3] += w * hi[1];
        }
    }

    int e = e0;
    for (; e + 8 <= e1; e += 8) {
        int2 q0 = ew[e + 0 + h], q1 = ew[e + 2 + h];
        int2 q2 = ew[e + 4 + h], q3 = ew[e + 6 + h];
        unsigned int r0 = T32[(size_t)q0.x * 32 + li];
        unsigned int r1 = T32[(size_t)q1.x * 32 + li];
        unsigned int r2 = T32[(size_t)q2.x * 32 + li];
        unsigned int r3 = T32[(size_t)q3.x * 32 + li];
        float w0 = __int_as_float(q0.y), w1 = __int_as_float(q1.y);
        float w2 = __int_as_float(q2.y), w3 = __int_as_float(q3.y);
        f32x2 a0 = __builtin_amdgcn_cvt_pk_f32_fp8((int)r0, 0);
        f32x2 b0 = __builtin_amdgcn_cvt_pk_f32_fp8((int)r0, 1);
        f32x2 a1 = __builtin_amdgcn_cvt_pk_f32_fp8((int)r1, 0);
        f32x2 b1 = __builtin_amdgcn_cvt_pk_f32_fp8((int)r1, 1);
        f32x2 a2 = __builtin_amdgcn_cvt_pk_f32_fp8((int)r2, 0);
        f32x2 b2 = __builtin_amdgcn_cvt_pk_f32_fp8((int)r2, 1);
        f32x2 a3 = __builtin_amdgcn_cvt_pk_f32_fp8((int)r3, 0);
        f32x2 b3 = __builtin_amdgcn_cvt_pk_f32_fp8((int)r3, 1);
        acc[0] += w0 * a0[0]; acc[1] += w0 * a0[1]; acc[2] += w0 * b0[0]; acc[3] += w0 * b0[1];
        acc[0] += w1 * a1[0]; acc[1] += w1 * a1[1]; acc[2] += w1 * b1[0]; acc[3] += w1 * b1[1];
        acc[0] += w2 * a2[0]; acc[1] += w2 * a2[1]; acc[2] += w2 * b2[0]; acc[3] += w2 * b2[1];
        acc[0] += w3 * a3[0]; acc[1] += w3 * a3[1]; acc[2] += w3 * b3[0]; acc[3] += w3 * b3[1];
    }
    for (; e + 4 <= e1; e += 4) {
        int2 q0 = ew[e + 0 + h], q1 = ew[e + 2 + h];
        unsigned int r0 = T32[(size_t)q0.x * 32 + li];
        unsigned int r1 = T32[(size_t)q1.x * 32 + li];
        float w0 = __int_as_float(q0.y), w1 = __int_as_float(q1.y);
        f32x2 a0 = __builtin_amdgcn_cvt_pk_f32_fp8((int)r0, 0);
        f32x2 b0 = __builtin_amdgcn_cvt_pk_f32_fp8((int)r0, 1);
        f32x2 a1 = __builtin_amdgcn_cvt_pk_f32_fp8((int)r1, 0);
        f32x2 b1 = __builtin_amdgcn_cvt_pk_f32_fp8((int)r1, 1);
        acc[0] += w0 * a0[0]; acc[1] += w0 * a0[1]; acc[2] += w0 * b0[0]; acc[3] += w0 * b0[1];
        acc[0] += w1 * a1[0]; acc[1] += w1 * a1[1]; acc[2] += w1 * b1[0]; acc[3] += w1 * b1[1];
    }
    for (; e < e1; e += 2) {
        int idx = e + h;
        if (idx < e1) {
            int2 q = ew[idx];
            unsigned int r = T32[(size_t)q.x * 32 + li];
            float w = __int_as_float(q.y);
            f32x2 a = __builtin_amdgcn_cvt_pk_f32_fp8((int)r, 0);
            f32x2 b = __builtin_amdgcn_cvt_pk_f32_fp8((int)r, 1);
            acc[0] += w * a[0]; acc[1] += w * a[1];
            acc[2] += w * b[0]; acc[3] += w * b[1];
        }
    }

    // merge halves
#pragma unroll
    for (int i = 0; i < 4; ++i)
        acc[i] += __shfl_xor(acc[i], 32, 64);

    if (h == 0) {
        float4 b = ((const float4*)bias)[li];
        __half2 o01 = __floats2half2_rn(fmaxf(acc[0] + b.x, 0.f), fmaxf(acc[1] + b.y, 0.f));
        __half2 o23 = __floats2half2_rn(fmaxf(acc[2] + b.z, 0.f), fmaxf(acc[3] + b.w, 0.f));
        *(int2*)(O + (size_t)v * DIM + li * 4) = make_int2(*(int*)&o01, *(int*)&o23);
    }
}

// ---------------------------------------------------------------------------
// Global mean pool (fp16 in, fp32 out), split-parallel: grid (n_graphs, POOL_SPLIT)
// ---------------------------------------------------------------------------
__global__ __launch_bounds__(64) void pool_k(const __half* __restrict__ H,
                                             const int* __restrict__ batch,
                                             float* __restrict__ G, int n) {
    int g = blockIdx.x;
    int part = blockIdx.y;

    int lo = 0, hi = n;
    while (lo < hi) { int m = (lo + hi) >> 1; if (batch[m] < g) lo = m + 1; else hi = m; }
    int start = lo;
    lo = start; hi = n;
    while (lo < hi) { int m = (lo + hi) >> 1; if (batch[m] < g + 1) lo = m + 1; else hi = m; }
    int end = lo;
    int cnt = end - start;
    if (cnt <= 0) return;
    float inv = 1.0f / (float)cnt;

    int lane = threadIdx.x;
    const __half2* H2 = (const __half2*)H;
    float2 s = make_float2(0.f, 0.f);
    for (int v = start + part; v < end; v += POOL_SPLIT) {
        float2 h = __half22float2(H2[(size_t)v * 64 + lane]);
        s.x += h.x; s.y += h.y;
    }
    atomicAdd(&G[g * DIM + 2 * lane + 0], s.x * inv);
    atomicAdd(&G[g * DIM + 2 * lane + 1], s.y * inv);
}

// ---------------------------------------------------------------------------
// Head: y = relu(g@lin1+b1); logits = y@lin2+b2; out = log_softmax(logits)
// ---------------------------------------------------------------------------
__global__ __launch_bounds__(128) void head_k(const float* __restrict__ G,
                                              const float* __restrict__ l1w,
                                              const float* __restrict__ l1b,
                                              const float* __restrict__ l2w,
                                              const float* __restrict__ l2b,
                                              float* __restrict__ out) {
    int g = blockIdx.x;
    int j = threadIdx.x;
    __shared__ float gs[128];
    __shared__ float2 red[128];

    gs[j] = G[g * 128 + j];
    __syncthreads();

    float acc = l1b[j];
    for (int k = 0; k < 128; ++k) acc += gs[k] * l1w[k * 128 + j];
    float y = fmaxf(acc, 0.f);

    red[j] = make_float2(y * l2w[j * 2 + 0], y * l2w[j * 2 + 1]);
    __syncthreads();
    for (int s = 64; s > 0; s >>= 1) {
        if (j < s) {
            red[j].x += red[j + s].x;
            red[j].y += red[j + s].y;
        }
        __syncthreads();
    }
    if (j == 0) {
        float l0 = red[0].x + l2b[0];
        float l1 = red[0].y + l2b[1];
        float m = fmaxf(l0, l1);
        float lse = m + logf(expf(l0 - m) + expf(l1 - m));
        out[g * 2 + 0] = l0 - lse;
        out[g * 2 + 1] = l1 - lse;
    }
}

// ---------------------------------------------------------------------------
// Launch
// ---------------------------------------------------------------------------
extern "C" void kernel_launch(void* const* d_in, const int* in_sizes, int n_in,
                              void* d_out, int out_size, void* d_ws, size_t ws_size,
                              hipStream_t stream) {
    const float* x       = (const float*)d_in[0];
    const int*   ei      = (const int*)d_in[1];
    const int*   batch   = (const int*)d_in[2];
    const float* conv_w  = (const float*)d_in[3];
    const float* conv_b  = (const float*)d_in[4];
    const float* lin1_w  = (const float*)d_in[5];
    const float* lin1_b  = (const float*)d_in[6];
    const float* lin2_w  = (const float*)d_in[7];
    const float* lin2_b  = (const float*)d_in[8];
    float* out = (float*)d_out;

    const int n = in_sizes[0] / DIM;      // 100000
    const int E = in_sizes[1] / 2;        // 1600000
    const int n_graphs = 128;
    const int NBIN = (n + (1 << BINSH) - 1) >> BINSH;   // 98 dst-bins

    const int* src = ei;
    const int* dst = ei + E;

    // workspace layout (all 256B aligned)
    char* p = (char*)d_ws;
    auto alloc = [&](size_t bytes) {
        char* r = p;
        p += (bytes + 255) & ~(size_t)255;
        return r;
    };
    __half*        bufH    = (__half*)alloc((size_t)n * DIM * 2);       // agg output (fp16)
    unsigned int*  bufT    = (unsigned int*)alloc((size_t)n * DIM);     // gemm output (fp8)
    float*         dis     = (float*)alloc((size_t)n * 4);
    int*           rowptr  = (int*)alloc((size_t)(n + 1) * 4);
    int*           binsize = (int*)alloc(128 * 4);
    int*           binbase = (int*)alloc(132 * 4);
    int*           bincur  = (int*)alloc((size_t)NBIN * 16 * 4);
    int2*          tmp     = (int2*)alloc((size_t)E * 8);               // binned {src,dst}
    int2*          ew      = (int2*)alloc((size_t)E * 8);               // CSR {col, wgt}
    float*         gbuf    = (float*)alloc((size_t)n_graphs * DIM * 4);
    _Float16*      bp      = (_Float16*)alloc((size_t)3 * 2048 * 8 * 2);
    (void)ws_size;

    const int binBlocks = (E + EPB - 1) / EPB;      // 98

    hipMemsetAsync(binsize, 0, 128 * 4, stream);
    hipMemsetAsync(gbuf, 0, (size_t)n_graphs * DIM * 4, stream);
    wpack_k<<<24, 256, 0, stream>>>(conv_w, bp);
    bincount_k<<<binBlocks, 256, 0, stream>>>(dst, binsize, E, NBIN);
    binscan2_k<<<1, 128, 0, stream>>>(binsize, binbase, bincur, NBIN, E);
    bin_k<<<binBlocks, 256, 0, stream>>>(src, dst, bincur, tmp, E, NBIN);
    rowcnt_k<<<NBIN, 256, 0, stream>>>(tmp, binbase, rowptr, dis, n, E, NBIN);
    fill2_k<<<NBIN, 256, 0, stream>>>(tmp, rowptr, dis, ew, n);

    const int gemmBlocks = (n + 63) / 64;
    const int aggBlocks = (n + 3) / 4;

    // layer 0: x (fp32) -> bufT(fp8) -> bufH(fp16)
    gemm_k<false><<<gemmBlocks, 256, 0, stream>>>((const void*)x, bp + 0 * 16384, bufT, n);
    agg_k<<<aggBlocks, 256, 0, stream>>>(bufT, rowptr, ew, dis, conv_b + 0 * DIM, bufH, n);
    // layer 1
    gemm_k<true><<<gemmBlocks, 256, 0, stream>>>((const void*)bufH, bp + 1 * 16384, bufT, n);
    agg_k<<<aggBlocks, 256, 0, stream>>>(bufT, rowptr, ew, dis, conv_b + 1 * DIM, bufH, n);
    // layer 2
    gemm_k<true><<<gemmBlocks, 256, 0, stream>>>((const void*)bufH, bp + 2 * 16384, bufT, n);
    agg_k<<<aggBlocks, 256, 0, stream>>>(bufT, rowptr, ew, dis, conv_b + 2 * DIM, bufH, n);

    dim3 pgrid(n_graphs, POOL_SPLIT);
    pool_k<<<pgrid, 64, 0, stream>>>(bufH, batch, gbuf, n);
    head_k<<<n_graphs, 128, 0, stream>>>(gbuf, lin1_w, lin1_b, lin2_w, lin2_b, out);
}

// Round 13
// 450.772 us; speedup vs baseline: 1.9024x; 1.0193x over previous
//
#include <hip/hip_runtime.h>
#include <hip/hip_fp16.h>
#include <math.h>

#define DIM 128
#define POOL_SPLIT 32  // partial-sum blocks per graph
#define BINSH 10       // 1024 nodes per dst-bin
#define EPB 16384      // edges per bin_k block
#define ALH 136        // gemm A-tile LDS row stride in halves
// Build discipline (R6): per-EDGE global atomics ping-pong cache lines across
// the 8 non-coherent XCD L2s — catastrophic. All per-edge counting in LDS.
// Agg model (R8-R12): random-gather stream is CONCURRENCY-bound — achieved
// rate ~ outstanding gathers per wave (8 in flight -> 3.27 TB/s, 4 -> 2.02).
// This round: paired 4B-fp8 gathers (2 edges/wave-load) x 16-edge unroll
// = 8 gathers in flight at VGPR<=48 (R9's full-row 16-unroll cost occupancy).

typedef __attribute__((ext_vector_type(8))) _Float16 half8;
typedef __attribute__((ext_vector_type(4))) float f32x4;
typedef __attribute__((ext_vector_type(2))) float f32x2;

// ---------------------------------------------------------------------------
// Graph build: bincount -> binscan -> bin -> rowcnt -> fill2
// ---------------------------------------------------------------------------

__global__ __launch_bounds__(256) void bincount_k(const int* __restrict__ dst,
                                                  int* __restrict__ binsize,
                                                  int E, int NBIN) {
    __shared__ int h[128];
    const int t = threadIdx.x;
    if (t < 128) h[t] = 0;
    __syncthreads();
    const int e0 = blockIdx.x * EPB;
    const int e1 = min(e0 + EPB, E);
    for (int e = e0 + t; e < e1; e += 256)
        atomicAdd(&h[dst[e] >> BINSH], 1);
    __syncthreads();
    if (t < NBIN && h[t]) atomicAdd(&binsize[t], h[t]);
}

__global__ void binscan2_k(const int* __restrict__ binsize, int* __restrict__ binbase,
                           int* __restrict__ bincur, int NBIN, int E) {
    __shared__ int s[128];
    const int t = threadIdx.x;   // 128 threads
    int v = (t < NBIN) ? binsize[t] : 0;
    s[t] = v;
    __syncthreads();
    for (int off = 1; off < 128; off <<= 1) {
        int u = (t >= off) ? s[t - off] : 0;
        __syncthreads();
        s[t] += u;
        __syncthreads();
    }
    int excl = s[t] - v;
    if (t < NBIN) { binbase[t] = excl; bincur[t * 16] = excl; }
    if (t == 0) binbase[NBIN] = E;
}

__global__ __launch_bounds__(256) void bin_k(const int* __restrict__ src,
                                             const int* __restrict__ dst,
                                             int* __restrict__ bincur,
                                             int2* __restrict__ tmp, int E, int NBIN) {
    __shared__ int cur[128];
    const int t = threadIdx.x;
    if (t < 128) cur[t] = 0;
    __syncthreads();
    const int e0 = blockIdx.x * EPB;
    const int e1 = min(e0 + EPB, E);
    for (int e = e0 + t; e < e1; e += 256)
        atomicAdd(&cur[dst[e] >> BINSH], 1);
    __syncthreads();
    if (t < NBIN) {
        int h = cur[t];
        cur[t] = h ? atomicAdd(&bincur[t * 16], h) : 0;
    }
    __syncthreads();
    for (int e = e0 + t; e < e1; e += 256) {
        int d = dst[e], s = src[e];
        int pos = atomicAdd(&cur[d >> BINSH], 1);
        tmp[pos] = make_int2(s, d);
    }
}

__global__ __launch_bounds__(256) void rowcnt_k(const int2* __restrict__ tmp,
                                                const int* __restrict__ binbase,
                                                int* __restrict__ rowptr,
                                                float* __restrict__ dis,
                                                int n, int E, int NBIN) {
    __shared__ int cnt[1 << BINSH];
    __shared__ int part[256];
    const int b = blockIdx.x, t = threadIdx.x;
    for (int i = t; i < (1 << BINSH); i += 256) cnt[i] = 0;
    __syncthreads();
    const int ebeg = binbase[b], eend = binbase[b + 1];
    for (int e = ebeg + t; e < eend; e += 256)
        atomicAdd(&cnt[tmp[e].y & ((1 << BINSH) - 1)], 1);
    __syncthreads();
    int cc[4];
    cc[0] = cnt[t * 4 + 0]; cc[1] = cnt[t * 4 + 1];
    cc[2] = cnt[t * 4 + 2]; cc[3] = cnt[t * 4 + 3];
    int s = cc[0] + cc[1] + cc[2] + cc[3];
    part[t] = s;
    __syncthreads();
    for (int off = 1; off < 256; off <<= 1) {
        int u = (t >= off) ? part[t - off] : 0;
        __syncthreads();
        part[t] += u;
        __syncthreads();
    }
    int off0 = ebeg + part[t] - s;
    int node0 = (b << BINSH) + t * 4;
    int pre = 0;
#pragma unroll
    for (int j = 0; j < 4; ++j) {
        int node = node0 + j;
        if (node < n) {
            rowptr[node] = off0 + pre;
            dis[node] = rsqrtf((float)(cc[j] + 1));
        }
        pre += cc[j];
    }
    if (b == NBIN - 1 && t == 0) rowptr[n] = E;
}

__global__ __launch_bounds__(256) void fill2_k(const int2* __restrict__ tmp,
                                               const int* __restrict__ rowptr,
                                               const float* __restrict__ dis,
                                               int2* __restrict__ ew, int n) {
    __shared__ int lcur[1 << BINSH];
    const int base_node = blockIdx.x << BINSH;
    const int t = threadIdx.x;
    for (int i = t; i < (1 << BINSH); i += 256)
        if (base_node + i < n) lcur[i] = rowptr[base_node + i];
    const int e_begin = rowptr[base_node];
    const int e_end   = rowptr[min(base_node + (1 << BINSH), n)];
    __syncthreads();
    for (int e = e_begin + t; e < e_end; e += 256) {
        int2 r = tmp[e];
        float w = dis[r.x] * dis[r.y];
        int q = atomicAdd(&lcur[r.y & ((1 << BINSH) - 1)], 1);
        ew[q] = make_int2(r.x, __float_as_int(w));
    }
}

// ---------------------------------------------------------------------------
// Weight pre-pack: conv_w (fp32 [k][col]) -> fp16 MFMA A-operand fragment order
// ---------------------------------------------------------------------------
__global__ void wpack_k(const float* __restrict__ conv_w, _Float16* __restrict__ bp) {
    int g = blockIdx.x * 256 + threadIdx.x;   // 3 * 2048
    if (g >= 3 * 2048) return;
    int l = g >> 11;
    int rem = g & 2047;
    int c = rem >> 8;
    int f = (rem >> 6) & 3;
    int lane = rem & 63;
    const float* W = conv_w + l * DIM * DIM;
    int kbase = f * 32 + (lane >> 4) * 8;
    int col = c * 16 + (lane & 15);
    _Float16* d = bp + ((size_t)l * 2048 + (size_t)(c * 4 + f) * 64 + lane) * 8;
#pragma unroll
    for (int j = 0; j < 8; ++j)
        d[j] = (_Float16)W[(kbase + j) * DIM + col];
}

// ---------------------------------------------------------------------------
// MFMA GEMM: T[n,128](fp8 e4m3) = A[n,128] @ W ; fp32 accumulate. D^T via
// operand swap -> lane owns 4 consecutive cols -> one packed 4B fp8 store.
// Word w of row contains dims 4w..4w+3.
// ---------------------------------------------------------------------------
template <bool FP16IN>
__global__ __launch_bounds__(256) void gemm_k(const void* __restrict__ Ain,
                                              const _Float16* __restrict__ Bp,
                                              unsigned int* __restrict__ T32, int n) {
    __shared__ _Float16 Al[64 * ALH];
    const int t = threadIdx.x;
    const int r0 = blockIdx.x * 64;
    const int nrows = min(64, n - r0);

    if (FP16IN) {
        const _Float16* A = (const _Float16*)Ain;
        for (int idx = t; idx < 64 * 16; idx += 256) {
            int row = idx >> 4, c = idx & 15;
            half8 v = {};
            if (row < nrows) v = *(const half8*)(A + (size_t)(r0 + row) * DIM + c * 8);
            *(half8*)&Al[row * ALH + c * 8] = v;
        }
    } else {
        const float* A = (const float*)Ain;
        for (int idx = t; idx < 64 * 32; idx += 256) {
            int row = idx >> 5, c = idx & 31;
            float4 v = make_float4(0.f, 0.f, 0.f, 0.f);
            if (row < nrows) v = ((const float4*)(A + (size_t)(r0 + row) * DIM))[c];
            __half2 h01 = __floats2half2_rn(v.x, v.y);
            __half2 h23 = __floats2half2_rn(v.z, v.w);
            *(int2*)&Al[row * ALH + c * 4] = make_int2(*(int*)&h01, *(int*)&h23);
        }
    }
    __syncthreads();

    const int lane = t & 63;
    const int wave = t >> 6;
    const int quad = lane >> 4;
    const int m    = lane & 15;
    const int lrow = wave * 16 + m;
    const int row  = r0 + lrow;

    half8 a[4];
#pragma unroll
    for (int f = 0; f < 4; ++f)
        a[f] = *(const half8*)&Al[lrow * ALH + f * 32 + quad * 8];

    const half8* B8 = (const half8*)Bp;   // 32KB/layer, hot in L1
#pragma unroll
    for (int c = 0; c < 8; ++c) {
        f32x4 acc = {0.f, 0.f, 0.f, 0.f};
#pragma unroll
        for (int f = 0; f < 4; ++f) {
            half8 b = B8[(c * 4 + f) * 64 + lane];
            acc = __builtin_amdgcn_mfma_f32_16x16x32_f16(b, a[f], acc, 0, 0, 0);
        }
        if (row < n) {
            int r = 0;
            r = __builtin_amdgcn_cvt_pk_fp8_f32(acc[0], acc[1], r, 0);
            r = __builtin_amdgcn_cvt_pk_fp8_f32(acc[2], acc[3], r, 1);
            T32[(size_t)row * 32 + c * 4 + quad] = (unsigned int)r;
        }
    }
}

// ---------------------------------------------------------------------------
// Aggregation: O[v] = relu( dis[v]^2 * T[v] + sum_e wgt[e]*T[col[e]] + b )
// one wave per node; lane = (half h, word li): loads uint = 4 fp8 dims at
// word li of its half's edge row -> ONE wave-gather serves TWO edges.
// 16-edge unroll = 8 gathers in flight (concurrency is the knob: R8-R12).
// Cross-half merge: shfl_xor(32) x4 at the end; lanes 0-31 store 8B fp16.
// ---------------------------------------------------------------------------
__global__ __launch_bounds__(256) void agg_k(const unsigned int* __restrict__ T32,
                                             const int* __restrict__ rowptr,
                                             const int2* __restrict__ ew,
                                             const float* __restrict__ dis,
                                             const float* __restrict__ bias,
                                             __half* __restrict__ O, int n) {
    const int lane = threadIdx.x & 63;
    const int h    = lane >> 5;        // which edge of the pair
    const int li   = lane & 31;        // word (4 dims) within row
    const int v = blockIdx.x * 4 + (threadIdx.x >> 6);
    if (v >= n) return;

    float dv = dis[v];
    int e0 = rowptr[v], e1 = rowptr[v + 1];

    f32x4 acc = {0.f, 0.f, 0.f, 0.f};
    // self term (half 0 only; half 1's load is a broadcast of the same line)
    {
        unsigned int r = T32[(size_t)v * 32 + li];
        if (h == 0) {
            f32x2 lo = __builtin_amdgcn_cvt_pk_f32_fp8((int)r, 0);
            f32x2 hi = __builtin_amdgcn_cvt_pk_f32_fp8((int)r, 1);
            float w = dv * dv;
            acc[0] += w * lo[0]; acc[1] += w * lo[1];
            acc[2] += w * hi[0]; acc[3] += w * hi[1];
        }
    }

    int e = e0;
    for (; e + 16 <= e1; e += 16) {
        int2 q0 = ew[e +  0 + h], q1 = ew[e +  2 + h];
        int2 q2 = ew[e +  4 + h], q3 = ew[e +  6 + h];
        int2 q4 = ew[e +  8 + h], q5 = ew[e + 10 + h];
        int2 q6 = ew[e + 12 + h], q7 = ew[e + 14 + h];
        unsigned int r0 = T32[(size_t)q0.x * 32 + li];
        unsigned int r1 = T32[(size_t)q1.x * 32 + li];
        unsigned int r2 = T32[(size_t)q2.x * 32 + li];
        unsigned int r3 = T32[(size_t)q3.x * 32 + li];
        unsigned int r4 = T32[(size_t)q4.x * 32 + li];
        unsigned int r5 = T32[(size_t)q5.x * 32 + li];
        unsigned int r6 = T32[(size_t)q6.x * 32 + li];
        unsigned int r7 = T32[(size_t)q7.x * 32 + li];
        float w0 = __int_as_float(q0.y), w1 = __int_as_float(q1.y);
        float w2 = __int_as_float(q2.y), w3 = __int_as_float(q3.y);
        float w4 = __int_as_float(q4.y), w5 = __int_as_float(q5.y);
        float w6 = __int_as_float(q6.y), w7 = __int_as_float(q7.y);
        f32x2 a0 = __builtin_amdgcn_cvt_pk_f32_fp8((int)r0, 0);
        f32x2 b0 = __builtin_amdgcn_cvt_pk_f32_fp8((int)r0, 1);
        f32x2 a1 = __builtin_amdgcn_cvt_pk_f32_fp8((int)r1, 0);
        f32x2 b1 = __builtin_amdgcn_cvt_pk_f32_fp8((int)r1, 1);
        f32x2 a2 = __builtin_amdgcn_cvt_pk_f32_fp8((int)r2, 0);
        f32x2 b2 = __builtin_amdgcn_cvt_pk_f32_fp8((int)r2, 1);
        f32x2 a3 = __builtin_amdgcn_cvt_pk_f32_fp8((int)r3, 0);
        f32x2 b3 = __builtin_amdgcn_cvt_pk_f32_fp8((int)r3, 1);
        f32x2 a4 = __builtin_amdgcn_cvt_pk_f32_fp8((int)r4, 0);
        f32x2 b4 = __builtin_amdgcn_cvt_pk_f32_fp8((int)r4, 1);
        f32x2 a5 = __builtin_amdgcn_cvt_pk_f32_fp8((int)r5, 0);
        f32x2 b5 = __builtin_amdgcn_cvt_pk_f32_fp8((int)r5, 1);
        f32x2 a6 = __builtin_amdgcn_cvt_pk_f32_fp8((int)r6, 0);
        f32x2 b6 = __builtin_amdgcn_cvt_pk_f32_fp8((int)r6, 1);
        f32x2 a7 = __builtin_amdgcn_cvt_pk_f32_fp8((int)r7, 0);
        f32x2 b7 = __builtin_amdgcn_cvt_pk_f32_fp8((int)r7, 1);
        acc[0] += w0 * a0[0]; acc[1] += w0 * a0[1]; acc[2] += w0 * b0[0]; acc[3] += w0 * b0[1];
        acc[0] += w1 * a1[0]; acc[1] += w1 * a1[1]; acc[2] += w1 * b1[0]; acc[3] += w1 * b1[1];
        acc[0] += w2 * a2[0]; acc[1] += w2 * a2[1]; acc[2] += w2 * b2[0]; acc[3] += w2 * b2[1];
        acc[0] += w3 * a3[0]; acc[1] += w3 * a3[1]; acc[2] += w3 * b3[0]; acc[3] += w3 * b3[1];
        acc[0] += w4 * a4[0]; acc[1] += w4 * a4[1]; acc[2] += w4 * b4[0]; acc[3] += w4 * b4[1];
        acc[0] += w5 * a5[0]; acc[1] += w5 * a5[1]; acc[2] += w5 * b5[0]; acc[3] += w5 * b5[1];
        acc[0] += w6 * a6[0]; acc[1] += w6 * a6[1]; acc[2] += w6 * b6[0]; acc[3] += w6 * b6[1];
        acc[0] += w7 * a7[0]; acc[1] += w7 * a7[1]; acc[2] += w7 * b7[0]; acc[3] += w7 * b7[1];
    }
    for (; e + 8 <= e1; e += 8) {
        int2 q0 = ew[e + 0 + h], q1 = ew[e + 2 + h];
        int2 q2 = ew[e + 4 + h], q3 = ew[e + 6 + h];
        unsigned int r0 = T32[(size_t)q0.x * 32 + li];
        unsigned int r1 = T32[(size_t)q1.x * 32 + li];
        unsigned int r2 = T32[(size_t)q2.x * 32 + li];
        unsigned int r3 = T32[(size_t)q3.x * 32 + li];
        float w0 = __int_as_float(q0.y), w1 = __int_as_float(q1.y);
        float w2 = __int_as_float(q2.y), w3 = __int_as_float(q3.y);
        f32x2 a0 = __builtin_amdgcn_cvt_pk_f32_fp8((int)r0, 0);
        f32x2 b0 = __builtin_amdgcn_cvt_pk_f32_fp8((int)r0, 1);
        f32x2 a1 = __builtin_amdgcn_cvt_pk_f32_fp8((int)r1, 0);
        f32x2 b1 = __builtin_amdgcn_cvt_pk_f32_fp8((int)r1, 1);
        f32x2 a2 = __builtin_amdgcn_cvt_pk_f32_fp8((int)r2, 0);
        f32x2 b2 = __builtin_amdgcn_cvt_pk_f32_fp8((int)r2, 1);
        f32x2 a3 = __builtin_amdgcn_cvt_pk_f32_fp8((int)r3, 0);
        f32x2 b3 = __builtin_amdgcn_cvt_pk_f32_fp8((int)r3, 1);
        acc[0] += w0 * a0[0]; acc[1] += w0 * a0[1]; acc[2] += w0 * b0[0]; acc[3] += w0 * b0[1];
        acc[0] += w1 * a1[0]; acc[1] += w1 * a1[1]; acc[2] += w1 * b1[0]; acc[3] += w1 * b1[1];
        acc[0] += w2 * a2[0]; acc[1] += w2 * a2[1]; acc[2] += w2 * b2[0]; acc[3] += w2 * b2[1];
        acc[0] += w3 * a3[0]; acc[1] += w3 * a3[1]; acc[2] += w3 * b3[0]; acc[3] += w3 * b3[1];
    }
    for (; e + 4 <= e1; e += 4) {
        int2 q0 = ew[e + 0 + h], q1 = ew[e + 2 + h];
        unsigned int r0 = T32[(size_t)q0.x * 32 + li];
        unsigned int r1 = T32[(size_t)q1.x * 32 + li];
        float w0 = __int_as_float(q0.y), w1 = __int_as_float(q1.y);
        f32x2 a0 = __builtin_amdgcn_cvt_pk_f32_fp8((int)r0, 0);
        f32x2 b0 = __builtin_amdgcn_cvt_pk_f32_fp8((int)r0, 1);
        f32x2 a1 = __builtin_amdgcn_cvt_pk_f32_fp8((int)r1, 0);
        f32x2 b1 = __builtin_amdgcn_cvt_pk_f32_fp8((int)r1, 1);
        acc[0] += w0 * a0[0]; acc[1] += w0 * a0[1]; acc[2] += w0 * b0[0]; acc[3] += w0 * b0[1];
        acc[0] += w1 * a1[0]; acc[1] += w1 * a1[1]; acc[2] += w1 * b1[0]; acc[3] += w1 * b1[1];
    }
    for (; e < e1; e += 2) {
        int idx = e + h;
        if (idx < e1) {
            int2 q = ew[idx];
            unsigned int r = T32[(size_t)q.x * 32 + li];
            float w = __int_as_float(q.y);
            f32x2 a = __builtin_amdgcn_cvt_pk_f32_fp8((int)r, 0);
            f32x2 b = __builtin_amdgcn_cvt_pk_f32_fp8((int)r, 1);
            acc[0] += w * a[0]; acc[1] += w * a[1];
            acc[2] += w * b[0]; acc[3] += w * b[1];
        }
    }

    // merge halves
#pragma unroll
    for (int i = 0; i < 4; ++i)
        acc[i] += __shfl_xor(acc[i], 32, 64);

    if (h == 0) {
        float4 b = ((const float4*)bias)[li];
        __half2 o01 = __floats2half2_rn(fmaxf(acc[0] + b.x, 0.f), fmaxf(acc[1] + b.y, 0.f));
        __half2 o23 = __floats2half2_rn(fmaxf(acc[2] + b.z, 0.f), fmaxf(acc[3] + b.w, 0.f));
        *(int2*)(O + (size_t)v * DIM + li * 4) = make_int2(*(int*)&o01, *(int*)&o23);
    }
}

// ---------------------------------------------------------------------------
// Global mean pool (fp16 in, fp32 out), split-parallel: grid (n_graphs, POOL_SPLIT)
// ---------------------------------------------------------------------------
__global__ __launch_bounds__(64) void pool_k(const __half* __restrict__ H,
                                             const int* __restrict__ batch,
                                             float* __restrict__ G, int n) {
    int g = blockIdx.x;
    int part = blockIdx.y;

    int lo = 0, hi = n;
    while (lo < hi) { int m = (lo + hi) >> 1; if (batch[m] < g) lo = m + 1; else hi = m; }
    int start = lo;
    lo = start; hi = n;
    while (lo < hi) { int m = (lo + hi) >> 1; if (batch[m] < g + 1) lo = m + 1; else hi = m; }
    int end = lo;
    int cnt = end - start;
    if (cnt <= 0) return;
    float inv = 1.0f / (float)cnt;

    int lane = threadIdx.x;
    const __half2* H2 = (const __half2*)H;
    float2 s = make_float2(0.f, 0.f);
    for (int v = start + part; v < end; v += POOL_SPLIT) {
        float2 h = __half22float2(H2[(size_t)v * 64 + lane]);
        s.x += h.x; s.y += h.y;
    }
    atomicAdd(&G[g * DIM + 2 * lane + 0], s.x * inv);
    atomicAdd(&G[g * DIM + 2 * lane + 1], s.y * inv);
}

// ---------------------------------------------------------------------------
// Head: y = relu(g@lin1+b1); logits = y@lin2+b2; out = log_softmax(logits)
// ---------------------------------------------------------------------------
__global__ __launch_bounds__(128) void head_k(const float* __restrict__ G,
                                              const float* __restrict__ l1w,
                                              const float* __restrict__ l1b,
                                              const float* __restrict__ l2w,
                                              const float* __restrict__ l2b,
                                              float* __restrict__ out) {
    int g = blockIdx.x;
    int j = threadIdx.x;
    __shared__ float gs[128];
    __shared__ float2 red[128];

    gs[j] = G[g * 128 + j];
    __syncthreads();

    float acc = l1b[j];
    for (int k = 0; k < 128; ++k) acc += gs[k] * l1w[k * 128 + j];
    float y = fmaxf(acc, 0.f);

    red[j] = make_float2(y * l2w[j * 2 + 0], y * l2w[j * 2 + 1]);
    __syncthreads();
    for (int s = 64; s > 0; s >>= 1) {
        if (j < s) {
            red[j].x += red[j + s].x;
            red[j].y += red[j + s].y;
        }
        __syncthreads();
    }
    if (j == 0) {
        float l0 = red[0].x + l2b[0];
        float l1 = red[0].y + l2b[1];
        float m = fmaxf(l0, l1);
        float lse = m + logf(expf(l0 - m) + expf(l1 - m));
        out[g * 2 + 0] = l0 - lse;
        out[g * 2 + 1] = l1 - lse;
    }
}

// ---------------------------------------------------------------------------
// Launch
// ---------------------------------------------------------------------------
extern "C" void kernel_launch(void* const* d_in, const int* in_sizes, int n_in,
                              void* d_out, int out_size, void* d_ws, size_t ws_size,
                              hipStream_t stream) {
    const float* x       = (const float*)d_in[0];
    const int*   ei      = (const int*)d_in[1];
    const int*   batch   = (const int*)d_in[2];
    const float* conv_w  = (const float*)d_in[3];
    const float* conv_b  = (const float*)d_in[4];
    const float* lin1_w  = (const float*)d_in[5];
    const float* lin1_b  = (const float*)d_in[6];
    const float* lin2_w  = (const float*)d_in[7];
    const float* lin2_b  = (const float*)d_in[8];
    float* out = (float*)d_out;

    const int n = in_sizes[0] / DIM;      // 100000
    const int E = in_sizes[1] / 2;        // 1600000
    const int n_graphs = 128;
    const int NBIN = (n + (1 << BINSH) - 1) >> BINSH;   // 98 dst-bins

    const int* src = ei;
    const int* dst = ei + E;

    // workspace layout (all 256B aligned)
    char* p = (char*)d_ws;
    auto alloc = [&](size_t bytes) {
        char* r = p;
        p += (bytes + 255) & ~(size_t)255;
        return r;
    };
    __half*        bufH    = (__half*)alloc((size_t)n * DIM * 2);       // agg output (fp16)
    unsigned int*  bufT    = (unsigned int*)alloc((size_t)n * DIM);     // gemm output (fp8)
    float*         dis     = (float*)alloc((size_t)n * 4);
    int*           rowptr  = (int*)alloc((size_t)(n + 1) * 4);
    int*           binsize = (int*)alloc(128 * 4);
    int*           binbase = (int*)alloc(132 * 4);
    int*           bincur  = (int*)alloc((size_t)NBIN * 16 * 4);
    int2*          tmp     = (int2*)alloc((size_t)E * 8);               // binned {src,dst}
    int2*          ew      = (int2*)alloc((size_t)E * 8);               // CSR {col, wgt}
    float*         gbuf    = (float*)alloc((size_t)n_graphs * DIM * 4);
    _Float16*      bp      = (_Float16*)alloc((size_t)3 * 2048 * 8 * 2);
    (void)ws_size;

    const int binBlocks = (E + EPB - 1) / EPB;      // 98

    hipMemsetAsync(binsize, 0, 128 * 4, stream);
    hipMemsetAsync(gbuf, 0, (size_t)n_graphs * DIM * 4, stream);
    wpack_k<<<24, 256, 0, stream>>>(conv_w, bp);
    bincount_k<<<binBlocks, 256, 0, stream>>>(dst, binsize, E, NBIN);
    binscan2_k<<<1, 128, 0, stream>>>(binsize, binbase, bincur, NBIN, E);
    bin_k<<<binBlocks, 256, 0, stream>>>(src, dst, bincur, tmp, E, NBIN);
    rowcnt_k<<<NBIN, 256, 0, stream>>>(tmp, binbase, rowptr, dis, n, E, NBIN);
    fill2_k<<<NBIN, 256, 0, stream>>>(tmp, rowptr, dis, ew, n);

    const int gemmBlocks = (n + 63) / 64;
    const int aggBlocks = (n + 3) / 4;

    // layer 0: x (fp32) -> bufT(fp8) -> bufH(fp16)
    gemm_k<false><<<gemmBlocks, 256, 0, stream>>>((const void*)x, bp + 0 * 16384, bufT, n);
    agg_k<<<aggBlocks, 256, 0, stream>>>(bufT, rowptr, ew, dis, conv_b + 0 * DIM, bufH, n);
    // layer 1
    gemm_k<true><<<gemmBlocks, 256, 0, stream>>>((const void*)bufH, bp + 1 * 16384, bufT, n);
    agg_k<<<aggBlocks, 256, 0, stream>>>(bufT, rowptr, ew, dis, conv_b + 1 * DIM, bufH, n);
    // layer 2
    gemm_k<true><<<gemmBlocks, 256, 0, stream>>>((const void*)bufH, bp + 2 * 16384, bufT, n);
    agg_k<<<aggBlocks, 256, 0, stream>>>(bufT, rowptr, ew, dis, conv_b + 2 * DIM, bufH, n);

    dim3 pgrid(n_graphs, POOL_SPLIT);
    pool_k<<<pgrid, 64, 0, stream>>>(bufH, batch, gbuf, n);
    head_k<<<n_graphs, 128, 0, stream>>>(gbuf, lin1_w, lin1_b, lin2_w, lin2_b, out);
}